// Round 12
// baseline (476.021 us; speedup 1.0000x reference)
//
#include <hip/hip_runtime.h>
#include <math.h>

// ---------------- problem constants ----------------
#define DD   128
#define MM   4096
#define NSTEP 4
#define NEG_INF (-3.4e38f)

// ---------------- ws float-offset layout ----------------
#define WS_H0   0          // h slots [2][128]
#define WS_C0   256        // c slots [2][128]
#define WS_G    512        // (dead after fusion)
#define WS_RS   1024       // (dead)
#define WS_RE   1152       // (dead)
#define WS_GS   1280       // 4
#define WS_SIEI 1284       // (dead)
#define WS_RT   2048       // 4096
#define WS_Z0   8192       // f32 z0 [suf*2+k][4096][1024] = 16,777,216 floats
#define WS_W2S  (8192 + 16777216)       // W2 split: 2x262144 ushort = 262,144 floats
#define WS_USP  (WS_W2S + 262144)       // U split: 2x1,048,576 ushort = 1,048,576 floats
#define WS_WESP (WS_USP + 1048576)      // We split: 2x1,048,576 ushort = 1,048,576 floats
#define WS_END2 (WS_W2S + 262144)       // fast2: 68,190,208 B  (proven available)
#define WS_END4 (WS_WESP + 1048576)     // fast4: 76,578,816 B  (confirmed: ws ~256 MB)
#define W2SPLIT_N 262144
#define USPLIT_N  1048576
#define WESPLIT_N 1048576

typedef __attribute__((ext_vector_type(8))) short bf16x8;
typedef __attribute__((ext_vector_type(4))) float f32x4;
typedef __attribute__((ext_vector_type(4))) unsigned short u16x4;

static __device__ __forceinline__ unsigned short f2b(float x) {
  unsigned u = __float_as_uint(x);
  unsigned r = (u + 0x7fffu + ((u >> 16) & 1u)) >> 16;   // RNE
  return (unsigned short)r;
}
static __device__ __forceinline__ float b2f(unsigned short h) {
  return __uint_as_float(((unsigned)h) << 16);
}
static __device__ __forceinline__ void split4(float4 v, u16x4* h, u16x4* l) {
  unsigned short h0 = f2b(v.x), h1 = f2b(v.y), h2 = f2b(v.z), h3 = f2b(v.w);
  u16x4 hh = {h0, h1, h2, h3};
  u16x4 ll = {f2b(v.x - b2f(h0)), f2b(v.y - b2f(h1)),
              f2b(v.z - b2f(h2)), f2b(v.w - b2f(h3))};
  *h = hh; *l = ll;
}
static __device__ __forceinline__ float sigm(float x) {
  return 1.f / (1.f + expf(-x));
}

// =====================================================================
// init
// =====================================================================
__global__ void k_init(float* __restrict__ ws) {
  int t = threadIdx.x;
  if (t < 128) { ws[WS_H0 + t] = 0.f; ws[WS_C0 + t] = 0.f; }
}

// =====================================================================
// prep (merged): split W2 hi/lo; (fast4) split U and We-head hi/lo
// =====================================================================
__global__ void k_prep(const float* __restrict__ W2_s,
                       const float* __restrict__ W2_e,
                       const float* __restrict__ U,
                       const float* __restrict__ We_s, const float* __restrict__ We_e,
                       int do4, float* __restrict__ ws) {
  unsigned short* w2h = (unsigned short*)(ws + WS_W2S);
  unsigned short* w2l = w2h + W2SPLIT_N;
  unsigned short* uh = (unsigned short*)(ws + WS_USP);
  unsigned short* ul = uh + USPLIT_N;
  unsigned short* wh = (unsigned short*)(ws + WS_WESP);
  unsigned short* wl = wh + WESPLIT_N;
  int total = do4 ? (W2SPLIT_N + USPLIT_N + WESPLIT_N) : W2SPLIT_N;
  for (int i = blockIdx.x * blockDim.x + threadIdx.x; i < total;
       i += gridDim.x * blockDim.x) {
    if (i < W2SPLIT_N) {
      int suf = i >> 17;
      int rem = i & 131071;
      float v = (suf ? W2_e : W2_s)[rem];
      unsigned short h = f2b(v);
      w2h[i] = h; w2l[i] = f2b(v - b2f(h));
    } else if (i < W2SPLIT_N + USPLIT_N) {
      int j = i - W2SPLIT_N;
      float v = U[j];
      unsigned short h = f2b(v);
      uh[j] = h; ul[j] = f2b(v - b2f(h));
    } else {
      int j = i - W2SPLIT_N - USPLIT_N;
      int z = j >> 18;
      int rem = j & 262143;
      int e = rem >> 8, f = rem & 255;
      int suf = z >> 1, k = z & 1;
      const float* We = suf ? We_e : We_s;
      float v = We[((size_t)k * 1024 + e) * 384 + f];
      unsigned short h = f2b(v);
      wh[j] = h; wl[j] = f2b(v - b2f(h));
    }
  }
}

// =====================================================================
// k_z0m2 (fast4): Z0 GEMM from PRE-SPLIT bf16 (staging = pure copy)
// grid (32, 8, 4), 256 thr, tile 128x128, BK=32
// =====================================================================
__global__ __launch_bounds__(256) void k_z0m2(float* __restrict__ ws) {
  __shared__ unsigned short Ah[128][40];
  __shared__ unsigned short Al[128][40];
  __shared__ unsigned short Bh[128][40];
  __shared__ unsigned short Bl[128][40];
  float* z0 = ws + WS_Z0;
  const unsigned short* uh = (const unsigned short*)(ws + WS_USP);
  const unsigned short* ul = uh + USPLIT_N;
  const unsigned short* wh = (const unsigned short*)(ws + WS_WESP);
  const unsigned short* wl = wh + WESPLIT_N;

  int t = threadIdx.x;
  int lane = t & 63, wid = t >> 6;
  int wm = wid >> 1, wn = wid & 1;
  int lr = lane & 15, lk = (lane >> 4) * 8, lq = lane >> 4;
  int m0 = blockIdx.x * 128, e0 = blockIdx.y * 128;
  int z = blockIdx.z;
  const unsigned short* bh0 = wh + (size_t)z * 262144;
  const unsigned short* bl0 = wl + (size_t)z * 262144;

  f32x4 acc[4][4];
  f32x4 zz = {0.f, 0.f, 0.f, 0.f};
#pragma unroll
  for (int i = 0; i < 4; ++i)
#pragma unroll
    for (int n = 0; n < 4; ++n) acc[i][n] = zz;

  for (int kc = 0; kc < 8; ++kc) {
    int k0 = kc * 32;
    __syncthreads();
#pragma unroll
    for (int it = 0; it < 2; ++it) {
      int idx = t + it * 256;            // 512 tasks: row, 8-elem group
      int row = idx >> 2, q8 = (idx & 3) * 8;
      size_t goff = (size_t)(m0 + row) * 256 + k0 + q8;
      *(uint4*)&Ah[row][q8] = *(const uint4*)&uh[goff];
      *(uint4*)&Al[row][q8] = *(const uint4*)&ul[goff];
      size_t boff = (size_t)(e0 + row) * 256 + k0 + q8;
      *(uint4*)&Bh[row][q8] = *(const uint4*)&bh0[boff];
      *(uint4*)&Bl[row][q8] = *(const uint4*)&bl0[boff];
    }
    __syncthreads();
    bf16x8 ah[4], al[4], bh[4], bl[4];
#pragma unroll
    for (int i = 0; i < 4; ++i) {
      ah[i] = *(bf16x8*)&Ah[wm * 64 + i * 16 + lr][lk];
      al[i] = *(bf16x8*)&Al[wm * 64 + i * 16 + lr][lk];
    }
#pragma unroll
    for (int n = 0; n < 4; ++n) {
      bh[n] = *(bf16x8*)&Bh[wn * 64 + n * 16 + lr][lk];
      bl[n] = *(bf16x8*)&Bl[wn * 64 + n * 16 + lr][lk];
    }
#pragma unroll
    for (int i = 0; i < 4; ++i)
#pragma unroll
      for (int n = 0; n < 4; ++n) {
        acc[i][n] = __builtin_amdgcn_mfma_f32_16x16x32_bf16(ah[i], bh[n], acc[i][n], 0, 0, 0);
        acc[i][n] = __builtin_amdgcn_mfma_f32_16x16x32_bf16(ah[i], bl[n], acc[i][n], 0, 0, 0);
        acc[i][n] = __builtin_amdgcn_mfma_f32_16x16x32_bf16(al[i], bh[n], acc[i][n], 0, 0, 0);
      }
  }

  float* C = z0 + (size_t)z * MM * 1024;
#pragma unroll
  for (int i = 0; i < 4; ++i)
#pragma unroll
    for (int n = 0; n < 4; ++n)
#pragma unroll
      for (int r = 0; r < 4; ++r) {
        int row = m0 + wm * 64 + i * 16 + lq * 4 + r;
        int col = e0 + wn * 64 + n * 16 + lr;
        C[(size_t)row * 1024 + col] = acc[i][n][r];
      }
}

// =====================================================================
// k_z0m (fast2 fallback): inline-split Z0 GEMM
// =====================================================================
__global__ __launch_bounds__(256) void k_z0m(
    const float* __restrict__ U,
    const float* __restrict__ We_s, const float* __restrict__ We_e,
    float* __restrict__ ws) {
  __shared__ unsigned short Ah[128][40];
  __shared__ unsigned short Al[128][40];
  __shared__ unsigned short Bh[128][40];
  __shared__ unsigned short Bl[128][40];
  float* z0 = ws + WS_Z0;

  int t = threadIdx.x;
  int lane = t & 63, wid = t >> 6;
  int wm = wid >> 1, wn = wid & 1;
  int lr = lane & 15, lk = (lane >> 4) * 8, lq = lane >> 4;
  int m0 = blockIdx.x * 128, e0 = blockIdx.y * 128;
  int z = blockIdx.z;
  int suf = z >> 1, k = z & 1;
  const float* Wep = (suf ? We_e : We_s) + (size_t)k * 1024 * 384;

  f32x4 acc[4][4];
  f32x4 zz = {0.f, 0.f, 0.f, 0.f};
#pragma unroll
  for (int i = 0; i < 4; ++i)
#pragma unroll
    for (int n = 0; n < 4; ++n) acc[i][n] = zz;

  for (int kc = 0; kc < 8; ++kc) {
    int k0 = kc * 32;
    __syncthreads();
#pragma unroll
    for (int it = 0; it < 4; ++it) {
      int idx = t + it * 256;
      int row = idx >> 3, q = idx & 7;
      float4 va = *(const float4*)&U[(size_t)(m0 + row) * 256 + k0 + q * 4];
      u16x4 h, l; split4(va, &h, &l);
      *(u16x4*)&Ah[row][q * 4] = h;
      *(u16x4*)&Al[row][q * 4] = l;
      float4 vb = *(const float4*)&Wep[(size_t)(e0 + row) * 384 + k0 + q * 4];
      split4(vb, &h, &l);
      *(u16x4*)&Bh[row][q * 4] = h;
      *(u16x4*)&Bl[row][q * 4] = l;
    }
    __syncthreads();
    bf16x8 ah[4], al[4], bh[4], bl[4];
#pragma unroll
    for (int i = 0; i < 4; ++i) {
      ah[i] = *(bf16x8*)&Ah[wm * 64 + i * 16 + lr][lk];
      al[i] = *(bf16x8*)&Al[wm * 64 + i * 16 + lr][lk];
    }
#pragma unroll
    for (int n = 0; n < 4; ++n) {
      bh[n] = *(bf16x8*)&Bh[wn * 64 + n * 16 + lr][lk];
      bl[n] = *(bf16x8*)&Bl[wn * 64 + n * 16 + lr][lk];
    }
#pragma unroll
    for (int i = 0; i < 4; ++i)
#pragma unroll
      for (int n = 0; n < 4; ++n) {
        acc[i][n] = __builtin_amdgcn_mfma_f32_16x16x32_bf16(ah[i], bh[n], acc[i][n], 0, 0, 0);
        acc[i][n] = __builtin_amdgcn_mfma_f32_16x16x32_bf16(ah[i], bl[n], acc[i][n], 0, 0, 0);
        acc[i][n] = __builtin_amdgcn_mfma_f32_16x16x32_bf16(al[i], bh[n], acc[i][n], 0, 0, 0);
      }
  }

  float* C = z0 + (size_t)z * MM * 1024;
#pragma unroll
  for (int i = 0; i < 4; ++i)
#pragma unroll
    for (int n = 0; n < 4; ++n)
#pragma unroll
      for (int r = 0; r < 4; ++r) {
        int row = m0 + wm * 64 + i * 16 + lq * 4 + r;
        int col = e0 + wn * 64 + n * 16 + lr;
        C[(size_t)row * 1024 + col] = acc[i][n][r];
      }
}

// =====================================================================
// k_state2 (FUSED gates+r+rt): grid 65 x 256.
// Every block: redundant argmax -> si/ei; redundant gates (all 512 rows,
// same 16-thr/40-slice decomposition as proven k_gates); redundant h2/c2;
// Blocks 0..63: redundant r (all 256 rows, proven k_r decomposition) +
// own 64 rterm rows (proven k_rt decomposition).
// Block 64: h/c writeback (double-buffered slot) + gate logits + softmax.
// All redundant values bitwise-identical across blocks; no intra-kernel
// cross-block communication.
// =====================================================================
__global__ __launch_bounds__(256) void k_state2(
    const float* __restrict__ U,
    const float* __restrict__ Wih, const float* __restrict__ Whh,
    const float* __restrict__ bih, const float* __restrict__ bhh,
    const float* __restrict__ Wr_s, const float* __restrict__ br_s,
    const float* __restrict__ Wg_s, const float* __restrict__ bg_s,
    const float* __restrict__ We_s, const float* __restrict__ be_s,
    const float* __restrict__ Wr_e, const float* __restrict__ br_e,
    const float* __restrict__ Wg_e, const float* __restrict__ bg_e,
    const float* __restrict__ We_e, const float* __restrict__ be_e,
    const float* __restrict__ out, int step,
    float* __restrict__ ws) {
  __shared__ float ctx[640];    // [us(0..255) | ue(256..511) | h_prev(512..639)]
  __shared__ float gl[512];
  __shared__ float ctxR[640];   // [h2(0..127) | us(128..383) | ue(384..639)]
  __shared__ float rsh[256];
  __shared__ float rv[256];
  __shared__ int   ri[256];
  __shared__ int   sei[2];
  __shared__ float logit[4];
  int t = threadIdx.x, b = blockIdx.x;

  // ---- argmax of previous step's scores (redundant per block) ----
  if (step > 0) {
    int half = t >> 7, l = t & 127;
    const float* arr = out + (size_t)half * (NSTEP * MM) + (size_t)(step - 1) * MM;
    float bv = NEG_INF; int bi = 0;
    for (int i = l; i < MM; i += 128) {
      float v = arr[i];
      if (v > bv) { bv = v; bi = i; }
    }
    rv[t] = bv; ri[t] = bi;
    __syncthreads();
    for (int s = 64; s > 0; s >>= 1) {
      if (l < s) {
        float v2 = rv[t + s]; int i2 = ri[t + s];
        if (v2 > rv[t] || (v2 == rv[t] && i2 < ri[t])) { rv[t] = v2; ri[t] = i2; }
      }
      __syncthreads();
    }
    if (l == 0) sei[half] = ri[t];
    __syncthreads();
  } else {
    if (t == 0) { sei[0] = 0; sei[1] = MM - 1; }
    __syncthreads();
  }
  int si = sei[0], ei = sei[1];

  // ---- gather us/ue/h_prev ----
  ctx[t]       = U[(size_t)si * 256 + t];
  ctx[256 + t] = U[(size_t)ei * 256 + t];
  if (t < 128) ctx[512 + t] = ws[WS_H0 + (step & 1) * 128 + t];
  __syncthreads();
  ctxR[128 + t] = ctx[t];
  ctxR[384 + t] = ctx[256 + t];

  // ---- gates: all 512 rows, 16 thr/row (identical decomposition) ----
  {
    int sub = t & 15, rq = t >> 4;
    for (int it = 0; it < 32; ++it) {
      int row = it * 16 + rq;
      const float* wih = Wih + (size_t)row * 512;
      const float* whh = Whh + (size_t)row * 128;
      float acc = 0.f;
      int e0 = sub * 40;
#pragma unroll
      for (int e = e0; e < e0 + 40; e += 4) {
        float4 w = (e < 512) ? *(const float4*)&wih[e] : *(const float4*)&whh[e - 512];
        acc += w.x * ctx[e] + w.y * ctx[e + 1] + w.z * ctx[e + 2] + w.w * ctx[e + 3];
      }
#pragma unroll
      for (int off = 8; off > 0; off >>= 1) acc += __shfl_down(acc, off, 16);
      if (sub == 0) gl[row] = acc + bih[row] + bhh[row];
    }
  }
  __syncthreads();

  // ---- h2/c2 (redundant); block 64 writes next-step slots ----
  if (t < 128) {
    float ig = sigm(gl[t]);
    float fg = sigm(gl[128 + t]);
    float gg = tanhf(gl[256 + t]);
    float og = sigm(gl[384 + t]);
    float cp = ws[WS_C0 + (step & 1) * 128 + t];
    float c2 = fg * cp + ig * gg;
    float h2 = og * tanhf(c2);
    ctxR[t] = h2;
    if (b == 64) {
      ws[WS_C0 + ((step + 1) & 1) * 128 + t] = c2;
      ws[WS_H0 + ((step + 1) & 1) * 128 + t] = h2;
    }
  }
  __syncthreads();

  if (b < 64) {
    // ---- r: all 256 rows, 16 thr/row (identical decomposition) ----
    {
      int sub = t & 15, rq = t >> 4;
      for (int it = 0; it < 16; ++it) {
        int rr = it * 16 + rq;
        int suf = rr >> 7, i = rr & 127;
        const float* Wr = suf ? Wr_e : Wr_s;
        const float* br = suf ? br_e : br_s;
        const float* w = Wr + (size_t)i * 640;
        float acc = 0.f;
        int e0 = sub * 40;
#pragma unroll
        for (int e = e0; e < e0 + 40; e += 4) {
          float4 wv = *(const float4*)&w[e];
          acc += wv.x * ctxR[e] + wv.y * ctxR[e + 1] + wv.z * ctxR[e + 2] + wv.w * ctxR[e + 3];
        }
#pragma unroll
        for (int off = 8; off > 0; off >>= 1) acc += __shfl_down(acc, off, 16);
        if (sub == 0) rsh[rr] = tanhf(acc + br[i]);
      }
    }
    __syncthreads();
    // ---- rterm: own 64 rows, 4 thr/row (identical decomposition) ----
    {
      int lrw = t >> 2, sub = t & 3;
      int row = b * 64 + lrw;
      int suf = row >> 11, ke = row & 2047;
      const float* We = suf ? We_e : We_s;
      const float* be = suf ? be_e : be_s;
      const float* w = We + (size_t)ke * 384 + 256;
      const float* r = rsh + suf * 128;
      float acc = 0.f;
      int e0 = sub * 32;
#pragma unroll
      for (int e = e0; e < e0 + 32; e += 4) {
        float4 wv = *(const float4*)&w[e];
        acc += wv.x * r[e] + wv.y * r[e + 1] + wv.z * r[e + 2] + wv.w * r[e + 3];
      }
#pragma unroll
      for (int off = 2; off > 0; off >>= 1) acc += __shfl_down(acc, off, 4);
      if (sub == 0) ws[WS_RT + row] = acc + be[ke];
    }
  } else {
    // ---- block 64: gate logits + softmax ----
    if (t < 64) {
      int which = t >> 4, sub = t & 15;
      const float* Wg = (which < 2) ? Wg_s : Wg_e;
      const float* bg = (which < 2) ? bg_s : bg_e;
      int i = which & 1;
      const float* w = Wg + (size_t)i * 640;
      float acc = 0.f;
      int e0 = sub * 40;
#pragma unroll
      for (int e = e0; e < e0 + 40; e += 4) {
        float4 wv = *(const float4*)&w[e];
        acc += wv.x * ctxR[e] + wv.y * ctxR[e + 1] + wv.z * ctxR[e + 2] + wv.w * ctxR[e + 3];
      }
#pragma unroll
      for (int off = 8; off > 0; off >>= 1) acc += __shfl_down(acc, off, 16);
      if (sub == 0) logit[which] = acc + bg[i];
    }
    __syncthreads();
    if (t == 0) {
      float a = logit[0], bb = logit[1], mx = fmaxf(a, bb);
      float ea = expf(a - mx), eb = expf(bb - mx), s = ea + eb;
      ws[WS_GS + 0] = ea / s; ws[WS_GS + 1] = eb / s;
      a = logit[2]; bb = logit[3]; mx = fmaxf(a, bb);
      ea = expf(a - mx); eb = expf(bb - mx); s = ea + eb;
      ws[WS_GS + 2] = ea / s; ws[WS_GS + 3] = eb / s;
    }
  }
}

// =====================================================================
// k_score3: FUSED ph1+ph2+ph3 — FROZEN (proven R7/R11).  16-row tiles,
// grid (256, 2), 256 thr.
// =====================================================================
__global__ __launch_bounds__(256) void k_score3(
    const float* __restrict__ b2_a, const float* __restrict__ W3_a, const float* __restrict__ b3_a,
    const float* __restrict__ b2_b, const float* __restrict__ W3_b, const float* __restrict__ b3_b,
    float* __restrict__ out_a, float* __restrict__ out_b,
    float* __restrict__ ws) {
  __shared__ float rtm[2048];
  __shared__ float m1f[16][132];
  __shared__ float m2f[16][132];
  __shared__ float sj[16][8];

  const float* z0 = ws + WS_Z0;
  const unsigned short* w2base = (const unsigned short*)(ws + WS_W2S);

  int t = threadIdx.x;
  int suf = blockIdx.y;
  int m0 = blockIdx.x * 16;
  const float* b2 = suf ? b2_b : b2_a;
  const float* W3 = suf ? W3_b : W3_a;
  const float* b3 = suf ? b3_b : b3_a;
  float*     outp = suf ? out_b : out_a;
  const unsigned short* w2h = w2base + (size_t)suf * 131072;
  const unsigned short* w2l = w2base + W2SPLIT_N + (size_t)suf * 131072;

  for (int l = t; l < 2048; l += 256) rtm[l] = ws[WS_RT + suf * 2048 + l];
  float g0 = ws[WS_GS + suf * 2 + 0];
  float g1 = ws[WS_GS + suf * 2 + 1];
  __syncthreads();

  // ---- phase 1: maxout over p, mixture over k -> m1f (16 rows) ----
  {
    int row = t >> 4, c8 = (t & 15) * 8;
    const float* p0 = z0 + ((size_t)(suf * 2 + 0) * MM + m0 + row) * 1024 + c8;
    const float* p1 = z0 + ((size_t)(suf * 2 + 1) * MM + m0 + row) * 1024 + c8;
    float4 mxa0 = {NEG_INF, NEG_INF, NEG_INF, NEG_INF}, mxb0 = mxa0;
    float4 mxa1 = mxa0, mxb1 = mxa0;
#pragma unroll
    for (int pp = 0; pp < 8; ++pp) {
      float4 va0 = *(const float4*)&p0[pp * 128];
      float4 vb0 = *(const float4*)&p0[pp * 128 + 4];
      float4 ra0 = *(const float4*)&rtm[pp * 128 + c8];
      float4 rb0 = *(const float4*)&rtm[pp * 128 + c8 + 4];
      mxa0.x = fmaxf(mxa0.x, va0.x + ra0.x); mxa0.y = fmaxf(mxa0.y, va0.y + ra0.y);
      mxa0.z = fmaxf(mxa0.z, va0.z + ra0.z); mxa0.w = fmaxf(mxa0.w, va0.w + ra0.w);
      mxb0.x = fmaxf(mxb0.x, vb0.x + rb0.x); mxb0.y = fmaxf(mxb0.y, vb0.y + rb0.y);
      mxb0.z = fmaxf(mxb0.z, vb0.z + rb0.z); mxb0.w = fmaxf(mxb0.w, vb0.w + rb0.w);
      float4 va1 = *(const float4*)&p1[pp * 128];
      float4 vb1 = *(const float4*)&p1[pp * 128 + 4];
      float4 ra1 = *(const float4*)&rtm[1024 + pp * 128 + c8];
      float4 rb1 = *(const float4*)&rtm[1024 + pp * 128 + c8 + 4];
      mxa1.x = fmaxf(mxa1.x, va1.x + ra1.x); mxa1.y = fmaxf(mxa1.y, va1.y + ra1.y);
      mxa1.z = fmaxf(mxa1.z, va1.z + ra1.z); mxa1.w = fmaxf(mxa1.w, va1.w + ra1.w);
      mxb1.x = fmaxf(mxb1.x, vb1.x + rb1.x); mxb1.y = fmaxf(mxb1.y, vb1.y + rb1.y);
      mxb1.z = fmaxf(mxb1.z, vb1.z + rb1.z); mxb1.w = fmaxf(mxb1.w, vb1.w + rb1.w);
    }
    float4 o0 = {g0 * mxa0.x + g1 * mxa1.x, g0 * mxa0.y + g1 * mxa1.y,
                 g0 * mxa0.z + g1 * mxa1.z, g0 * mxa0.w + g1 * mxa1.w};
    float4 o1 = {g0 * mxb0.x + g1 * mxb1.x, g0 * mxb0.y + g1 * mxb1.y,
                 g0 * mxb0.z + g1 * mxb1.z, g0 * mxb0.w + g1 * mxb1.w};
    *(float4*)&m1f[row][c8] = o0;
    *(float4*)&m1f[row][c8 + 4] = o1;
  }
  __syncthreads();

  // ---- A fragments: split m1 rows hi/lo in registers ----
  int lane = t & 63, wid = t >> 6;
  int wcol = wid * 32;
  int lr = lane & 15, lk = (lane >> 4) * 8, lq = lane >> 4;
  bf16x8 ah[4], al[4];
#pragma unroll
  for (int kk = 0; kk < 4; ++kk) {
    float4 x0 = *(const float4*)&m1f[lr][kk * 32 + lk];
    float4 x1 = *(const float4*)&m1f[lr][kk * 32 + lk + 4];
    u16x4 h0, l0, h1, l1;
    split4(x0, &h0, &l0); split4(x1, &h1, &l1);
    bf16x8 a, b;
#pragma unroll
    for (int j = 0; j < 4; ++j) { a[j] = (short)h0[j]; a[4 + j] = (short)h1[j]; }
#pragma unroll
    for (int j = 0; j < 4; ++j) { b[j] = (short)l0[j]; b[4 + j] = (short)l1[j]; }
    ah[kk] = a; al[kk] = b;
  }

  // ---- phase 2: split-bf16 MFMA, B from global L2, maxout over sp ----
  float m2x[2][4];
#pragma unroll
  for (int nt = 0; nt < 2; ++nt)
#pragma unroll
    for (int r = 0; r < 4; ++r) m2x[nt][r] = NEG_INF;

  for (int sp = 0; sp < 8; ++sp) {
    f32x4 zz = {0.f, 0.f, 0.f, 0.f};
    f32x4 acc[2][2] = {{zz, zz}, {zz, zz}};
#pragma unroll
    for (int kk = 0; kk < 4; ++kk)
#pragma unroll
      for (int nt = 0; nt < 2; ++nt) {
        size_t boff = (size_t)(sp * 128 + wcol + nt * 16 + lr) * 128 + kk * 32 + lk;
        bf16x8 bhf = *(const bf16x8*)&w2h[boff];
        bf16x8 blf = *(const bf16x8*)&w2l[boff];
        int par = kk & 1;
        acc[nt][par] = __builtin_amdgcn_mfma_f32_16x16x32_bf16(ah[kk], bhf, acc[nt][par], 0, 0, 0);
        acc[nt][par] = __builtin_amdgcn_mfma_f32_16x16x32_bf16(ah[kk], blf, acc[nt][par], 0, 0, 0);
        acc[nt][par] = __builtin_amdgcn_mfma_f32_16x16x32_bf16(al[kk], bhf, acc[nt][par], 0, 0, 0);
      }
#pragma unroll
    for (int nt = 0; nt < 2; ++nt) {
      float bias = b2[sp * 128 + wcol + nt * 16 + lr];
#pragma unroll
      for (int r = 0; r < 4; ++r)
        m2x[nt][r] = fmaxf(m2x[nt][r], acc[nt][0][r] + acc[nt][1][r] + bias);
    }
  }
#pragma unroll
  for (int nt = 0; nt < 2; ++nt)
#pragma unroll
    for (int r = 0; r < 4; ++r)
      m2f[lq * 4 + r][wcol + nt * 16 + lr] = m2x[nt][r];
  __syncthreads();

  // ---- phase 3: [m1|m2] @ W3^T + b3, max over 8 ----
  if (t < 128) {
    int row = t & 15, jp = t >> 4;
    const float* w3 = W3 + jp * 256;
    float acc = b3[jp];
    for (int f = 0; f < 128; f += 4) {
      float4 w = *(const float4*)&w3[f];
      acc += w.x * m1f[row][f] + w.y * m1f[row][f + 1] + w.z * m1f[row][f + 2] + w.w * m1f[row][f + 3];
    }
    for (int f = 0; f < 128; f += 4) {
      float4 w = *(const float4*)&w3[128 + f];
      acc += w.x * m2f[row][f] + w.y * m2f[row][f + 1] + w.z * m2f[row][f + 2] + w.w * m2f[row][f + 3];
    }
    sj[row][jp] = acc;
  }
  __syncthreads();
  if (t < 16) {
    float mx = sj[t][0];
#pragma unroll
    for (int j = 1; j < 8; ++j) mx = fmaxf(mx, sj[t][j]);
    outp[m0 + t] = mx;
  }
}

// =====================================================================
// slow fallback (tiny ws)
// =====================================================================
__global__ void k_score_slow(
    const float* __restrict__ U,
    const float* __restrict__ We_a, const float* __restrict__ We_b,
    const float* __restrict__ W2_a, const float* __restrict__ b2_a,
    const float* __restrict__ W3_a, const float* __restrict__ b3_a,
    const float* __restrict__ W2_b, const float* __restrict__ b2_b,
    const float* __restrict__ W3_b, const float* __restrict__ b3_b,
    float* __restrict__ out_a, float* __restrict__ out_b,
    const float* __restrict__ ws) {
  __shared__ float u[256];
  __shared__ float m1s[128];
  __shared__ float m2v[1024];
  __shared__ float m2s[128];
  __shared__ float sjs[8];
  int t = threadIdx.x;
  int m = blockIdx.x;
  int suf = blockIdx.y;
  const float* We = suf ? We_b : We_a;
  const float* W2 = suf ? W2_b : W2_a;
  const float* b2 = suf ? b2_b : b2_a;
  const float* W3 = suf ? W3_b : W3_a;
  const float* b3 = suf ? b3_b : b3_a;
  float*     outp = suf ? out_b : out_a;
  float g0 = ws[WS_GS + suf * 2 + 0];
  float g1 = ws[WS_GS + suf * 2 + 1];
  const float* rt = ws + WS_RT + suf * 2048;

  u[t] = U[(size_t)m * 256 + t];
  __syncthreads();
  if (t < 128) {
    float mx[2] = {NEG_INF, NEG_INF};
    for (int k = 0; k < 2; ++k)
      for (int pp = 0; pp < 8; ++pp) {
        int e = k * 1024 + pp * 128 + t;
        const float* w = We + (size_t)e * 384;
        float acc = rt[e];
        for (int f = 0; f < 256; f += 4) {
          float4 wv = *(const float4*)&w[f];
          acc += wv.x * u[f] + wv.y * u[f + 1] + wv.z * u[f + 2] + wv.w * u[f + 3];
        }
        mx[k] = fmaxf(mx[k], acc);
      }
    m1s[t] = g0 * mx[0] + g1 * mx[1];
  }
  __syncthreads();
  for (int e = t; e < 1024; e += 256) {
    const float* w = W2 + (size_t)e * 128;
    float acc = b2[e];
    for (int f = 0; f < 128; f += 4) {
      float4 wv = *(const float4*)&w[f];
      acc += wv.x * m1s[f] + wv.y * m1s[f + 1] + wv.z * m1s[f + 2] + wv.w * m1s[f + 3];
    }
    m2v[e] = acc;
  }
  __syncthreads();
  if (t < 128) {
    float mx = NEG_INF;
    for (int pp = 0; pp < 8; ++pp) mx = fmaxf(mx, m2v[pp * 128 + t]);
    m2s[t] = mx;
  }
  __syncthreads();
  if (t < 8) {
    const float* w3 = W3 + t * 256;
    float acc = b3[t];
    for (int f = 0; f < 128; ++f) acc += w3[f] * m1s[f];
    for (int f = 0; f < 128; ++f) acc += w3[128 + f] * m2s[f];
    sjs[t] = acc;
  }
  __syncthreads();
  if (t == 0) {
    float mx = sjs[0];
    for (int j = 1; j < 8; ++j) mx = fmaxf(mx, sjs[j]);
    outp[m] = mx;
  }
}

// =====================================================================
extern "C" void kernel_launch(void* const* d_in, const int* in_sizes, int n_in,
                              void* d_out, int out_size, void* d_ws, size_t ws_size,
                              hipStream_t stream) {
  const float* U    = (const float*)d_in[0];
  const float* Wih  = (const float*)d_in[1];
  const float* Whh  = (const float*)d_in[2];
  const float* bih  = (const float*)d_in[3];
  const float* bhh  = (const float*)d_in[4];
  const float* Wr_s = (const float*)d_in[5];
  const float* br_s = (const float*)d_in[6];
  const float* Wg_s = (const float*)d_in[7];
  const float* bg_s = (const float*)d_in[8];
  const float* We_s = (const float*)d_in[9];
  const float* be_s = (const float*)d_in[10];
  const float* W2_s = (const float*)d_in[11];
  const float* b2_s = (const float*)d_in[12];
  const float* W3_s = (const float*)d_in[13];
  const float* b3_s = (const float*)d_in[14];
  const float* Wr_e = (const float*)d_in[15];
  const float* br_e = (const float*)d_in[16];
  const float* Wg_e = (const float*)d_in[17];
  const float* bg_e = (const float*)d_in[18];
  const float* We_e = (const float*)d_in[19];
  const float* be_e = (const float*)d_in[20];
  const float* W2_e = (const float*)d_in[21];
  const float* b2_e = (const float*)d_in[22];
  const float* W3_e = (const float*)d_in[23];
  const float* b3_e = (const float*)d_in[24];
  float* out = (float*)d_out;
  float* ws  = (float*)d_ws;

  int fast4 = (ws_size >= (size_t)WS_END4 * 4);
  int fast2 = (ws_size >= (size_t)WS_END2 * 4);

  k_init<<<1, 128, 0, stream>>>(ws);
  if (fast2) {
    k_prep<<<768, 256, 0, stream>>>(W2_s, W2_e, U, We_s, We_e, fast4, ws);
    if (fast4) {
      k_z0m2<<<dim3(32, 8, 4), 256, 0, stream>>>(ws);
    } else {
      k_z0m<<<dim3(32, 8, 4), 256, 0, stream>>>(U, We_s, We_e, ws);
    }
  }

  for (int step = 0; step < NSTEP; ++step) {
    k_state2<<<65, 256, 0, stream>>>(U, Wih, Whh, bih, bhh,
                                     Wr_s, br_s, Wg_s, bg_s, We_s, be_s,
                                     Wr_e, br_e, Wg_e, bg_e, We_e, be_e,
                                     out, step, ws);

    float* out_s = out + (size_t)step * MM;
    float* out_e = out + (size_t)NSTEP * MM + (size_t)step * MM;

    if (fast2) {
      k_score3<<<dim3(256, 2), 256, 0, stream>>>(
          b2_s, W3_s, b3_s, b2_e, W3_e, b3_e, out_s, out_e, ws);
    } else {
      k_score_slow<<<dim3(MM, 2), 256, 0, stream>>>(
          U, We_s, We_e,
          W2_s, b2_s, W3_s, b3_s,
          W2_e, b2_e, W3_e, b3_e,
          out_s, out_e, ws);
    }
  }
}

// Round 13
// 291.556 us; speedup vs baseline: 1.6327x; 1.6327x over previous
//
#include <hip/hip_runtime.h>
#include <math.h>

// ---------------- problem constants ----------------
#define DD   128
#define MM   4096
#define NSTEP 4
#define NEG_INF (-3.4e38f)

// ---------------- ws float-offset layout ----------------
#define WS_H0   0          // h slots [2][128]
#define WS_C0   256        // c slots [2][128]
#define WS_G    512        // 512 gate preacts
#define WS_RS   1024       // 128
#define WS_RE   1152       // 128
#define WS_GS   1280       // 4
#define WS_SIEI 1284       // 2 ints
#define WS_RT   2048       // 4096
#define WS_Z0   8192       // f32 z0 [suf*2+k][4096][1024] = 16,777,216 floats
#define WS_W2S  (8192 + 16777216)       // W2 split: 2x262144 ushort = 262,144 floats
#define WS_USP  (WS_W2S + 262144)       // U split: 2x1,048,576 ushort = 1,048,576 floats
#define WS_WESP (WS_USP + 1048576)      // We split: 2x1,048,576 ushort = 1,048,576 floats
#define WS_END2 (WS_W2S + 262144)       // fast2: 68,190,208 B  (proven available)
#define WS_END4 (WS_WESP + 1048576)     // fast4: 76,578,816 B  (confirmed: ws ~256 MB)
#define W2SPLIT_N 262144
#define USPLIT_N  1048576
#define WESPLIT_N 1048576

typedef __attribute__((ext_vector_type(8))) short bf16x8;
typedef __attribute__((ext_vector_type(4))) float f32x4;
typedef __attribute__((ext_vector_type(4))) unsigned short u16x4;

static __device__ __forceinline__ unsigned short f2b(float x) {
  unsigned u = __float_as_uint(x);
  unsigned r = (u + 0x7fffu + ((u >> 16) & 1u)) >> 16;   // RNE
  return (unsigned short)r;
}
static __device__ __forceinline__ float b2f(unsigned short h) {
  return __uint_as_float(((unsigned)h) << 16);
}
static __device__ __forceinline__ void split4(float4 v, u16x4* h, u16x4* l) {
  unsigned short h0 = f2b(v.x), h1 = f2b(v.y), h2 = f2b(v.z), h3 = f2b(v.w);
  u16x4 hh = {h0, h1, h2, h3};
  u16x4 ll = {f2b(v.x - b2f(h0)), f2b(v.y - b2f(h1)),
              f2b(v.z - b2f(h2)), f2b(v.w - b2f(h3))};
  *h = hh; *l = ll;
}
static __device__ __forceinline__ float sigm(float x) {
  return 1.f / (1.f + expf(-x));
}

// =====================================================================
// init
// =====================================================================
__global__ void k_init(float* __restrict__ ws) {
  int t = threadIdx.x;
  if (t < 128) { ws[WS_H0 + t] = 0.f; ws[WS_C0 + t] = 0.f; }
}

// =====================================================================
// prep (merged): split W2 hi/lo; (fast4) split U and We-head hi/lo
// =====================================================================
__global__ void k_prep(const float* __restrict__ W2_s,
                       const float* __restrict__ W2_e,
                       const float* __restrict__ U,
                       const float* __restrict__ We_s, const float* __restrict__ We_e,
                       int do4, float* __restrict__ ws) {
  unsigned short* w2h = (unsigned short*)(ws + WS_W2S);
  unsigned short* w2l = w2h + W2SPLIT_N;
  unsigned short* uh = (unsigned short*)(ws + WS_USP);
  unsigned short* ul = uh + USPLIT_N;
  unsigned short* wh = (unsigned short*)(ws + WS_WESP);
  unsigned short* wl = wh + WESPLIT_N;
  int total = do4 ? (W2SPLIT_N + USPLIT_N + WESPLIT_N) : W2SPLIT_N;
  for (int i = blockIdx.x * blockDim.x + threadIdx.x; i < total;
       i += gridDim.x * blockDim.x) {
    if (i < W2SPLIT_N) {
      int suf = i >> 17;
      int rem = i & 131071;
      float v = (suf ? W2_e : W2_s)[rem];
      unsigned short h = f2b(v);
      w2h[i] = h; w2l[i] = f2b(v - b2f(h));
    } else if (i < W2SPLIT_N + USPLIT_N) {
      int j = i - W2SPLIT_N;
      float v = U[j];
      unsigned short h = f2b(v);
      uh[j] = h; ul[j] = f2b(v - b2f(h));
    } else {
      int j = i - W2SPLIT_N - USPLIT_N;
      int z = j >> 18;
      int rem = j & 262143;
      int e = rem >> 8, f = rem & 255;
      int suf = z >> 1, k = z & 1;
      const float* We = suf ? We_e : We_s;
      float v = We[((size_t)k * 1024 + e) * 384 + f];
      unsigned short h = f2b(v);
      wh[j] = h; wl[j] = f2b(v - b2f(h));
    }
  }
}

// =====================================================================
// k_z0m2 (fast4): Z0 GEMM from PRE-SPLIT bf16 (staging = pure copy)
// grid (32, 8, 4), 256 thr, tile 128x128, BK=32
// =====================================================================
__global__ __launch_bounds__(256) void k_z0m2(float* __restrict__ ws) {
  __shared__ unsigned short Ah[128][40];
  __shared__ unsigned short Al[128][40];
  __shared__ unsigned short Bh[128][40];
  __shared__ unsigned short Bl[128][40];
  float* z0 = ws + WS_Z0;
  const unsigned short* uh = (const unsigned short*)(ws + WS_USP);
  const unsigned short* ul = uh + USPLIT_N;
  const unsigned short* wh = (const unsigned short*)(ws + WS_WESP);
  const unsigned short* wl = wh + WESPLIT_N;

  int t = threadIdx.x;
  int lane = t & 63, wid = t >> 6;
  int wm = wid >> 1, wn = wid & 1;
  int lr = lane & 15, lk = (lane >> 4) * 8, lq = lane >> 4;
  int m0 = blockIdx.x * 128, e0 = blockIdx.y * 128;
  int z = blockIdx.z;
  const unsigned short* bh0 = wh + (size_t)z * 262144;
  const unsigned short* bl0 = wl + (size_t)z * 262144;

  f32x4 acc[4][4];
  f32x4 zz = {0.f, 0.f, 0.f, 0.f};
#pragma unroll
  for (int i = 0; i < 4; ++i)
#pragma unroll
    for (int n = 0; n < 4; ++n) acc[i][n] = zz;

  for (int kc = 0; kc < 8; ++kc) {
    int k0 = kc * 32;
    __syncthreads();
#pragma unroll
    for (int it = 0; it < 2; ++it) {
      int idx = t + it * 256;            // 512 tasks: row, 8-elem group
      int row = idx >> 2, q8 = (idx & 3) * 8;
      size_t goff = (size_t)(m0 + row) * 256 + k0 + q8;
      *(uint4*)&Ah[row][q8] = *(const uint4*)&uh[goff];
      *(uint4*)&Al[row][q8] = *(const uint4*)&ul[goff];
      size_t boff = (size_t)(e0 + row) * 256 + k0 + q8;
      *(uint4*)&Bh[row][q8] = *(const uint4*)&bh0[boff];
      *(uint4*)&Bl[row][q8] = *(const uint4*)&bl0[boff];
    }
    __syncthreads();
    bf16x8 ah[4], al[4], bh[4], bl[4];
#pragma unroll
    for (int i = 0; i < 4; ++i) {
      ah[i] = *(bf16x8*)&Ah[wm * 64 + i * 16 + lr][lk];
      al[i] = *(bf16x8*)&Al[wm * 64 + i * 16 + lr][lk];
    }
#pragma unroll
    for (int n = 0; n < 4; ++n) {
      bh[n] = *(bf16x8*)&Bh[wn * 64 + n * 16 + lr][lk];
      bl[n] = *(bf16x8*)&Bl[wn * 64 + n * 16 + lr][lk];
    }
#pragma unroll
    for (int i = 0; i < 4; ++i)
#pragma unroll
      for (int n = 0; n < 4; ++n) {
        acc[i][n] = __builtin_amdgcn_mfma_f32_16x16x32_bf16(ah[i], bh[n], acc[i][n], 0, 0, 0);
        acc[i][n] = __builtin_amdgcn_mfma_f32_16x16x32_bf16(ah[i], bl[n], acc[i][n], 0, 0, 0);
        acc[i][n] = __builtin_amdgcn_mfma_f32_16x16x32_bf16(al[i], bh[n], acc[i][n], 0, 0, 0);
      }
  }

  float* C = z0 + (size_t)z * MM * 1024;
#pragma unroll
  for (int i = 0; i < 4; ++i)
#pragma unroll
    for (int n = 0; n < 4; ++n)
#pragma unroll
      for (int r = 0; r < 4; ++r) {
        int row = m0 + wm * 64 + i * 16 + lq * 4 + r;
        int col = e0 + wn * 64 + n * 16 + lr;
        C[(size_t)row * 1024 + col] = acc[i][n][r];
      }
}

// =====================================================================
// k_z0m (fast2 fallback): inline-split Z0 GEMM
// =====================================================================
__global__ __launch_bounds__(256) void k_z0m(
    const float* __restrict__ U,
    const float* __restrict__ We_s, const float* __restrict__ We_e,
    float* __restrict__ ws) {
  __shared__ unsigned short Ah[128][40];
  __shared__ unsigned short Al[128][40];
  __shared__ unsigned short Bh[128][40];
  __shared__ unsigned short Bl[128][40];
  float* z0 = ws + WS_Z0;

  int t = threadIdx.x;
  int lane = t & 63, wid = t >> 6;
  int wm = wid >> 1, wn = wid & 1;
  int lr = lane & 15, lk = (lane >> 4) * 8, lq = lane >> 4;
  int m0 = blockIdx.x * 128, e0 = blockIdx.y * 128;
  int z = blockIdx.z;
  int suf = z >> 1, k = z & 1;
  const float* Wep = (suf ? We_e : We_s) + (size_t)k * 1024 * 384;

  f32x4 acc[4][4];
  f32x4 zz = {0.f, 0.f, 0.f, 0.f};
#pragma unroll
  for (int i = 0; i < 4; ++i)
#pragma unroll
    for (int n = 0; n < 4; ++n) acc[i][n] = zz;

  for (int kc = 0; kc < 8; ++kc) {
    int k0 = kc * 32;
    __syncthreads();
#pragma unroll
    for (int it = 0; it < 4; ++it) {
      int idx = t + it * 256;
      int row = idx >> 3, q = idx & 7;
      float4 va = *(const float4*)&U[(size_t)(m0 + row) * 256 + k0 + q * 4];
      u16x4 h, l; split4(va, &h, &l);
      *(u16x4*)&Ah[row][q * 4] = h;
      *(u16x4*)&Al[row][q * 4] = l;
      float4 vb = *(const float4*)&Wep[(size_t)(e0 + row) * 384 + k0 + q * 4];
      split4(vb, &h, &l);
      *(u16x4*)&Bh[row][q * 4] = h;
      *(u16x4*)&Bl[row][q * 4] = l;
    }
    __syncthreads();
    bf16x8 ah[4], al[4], bh[4], bl[4];
#pragma unroll
    for (int i = 0; i < 4; ++i) {
      ah[i] = *(bf16x8*)&Ah[wm * 64 + i * 16 + lr][lk];
      al[i] = *(bf16x8*)&Al[wm * 64 + i * 16 + lr][lk];
    }
#pragma unroll
    for (int n = 0; n < 4; ++n) {
      bh[n] = *(bf16x8*)&Bh[wn * 64 + n * 16 + lr][lk];
      bl[n] = *(bf16x8*)&Bl[wn * 64 + n * 16 + lr][lk];
    }
#pragma unroll
    for (int i = 0; i < 4; ++i)
#pragma unroll
      for (int n = 0; n < 4; ++n) {
        acc[i][n] = __builtin_amdgcn_mfma_f32_16x16x32_bf16(ah[i], bh[n], acc[i][n], 0, 0, 0);
        acc[i][n] = __builtin_amdgcn_mfma_f32_16x16x32_bf16(ah[i], bl[n], acc[i][n], 0, 0, 0);
        acc[i][n] = __builtin_amdgcn_mfma_f32_16x16x32_bf16(al[i], bh[n], acc[i][n], 0, 0, 0);
      }
  }

  float* C = z0 + (size_t)z * MM * 1024;
#pragma unroll
  for (int i = 0; i < 4; ++i)
#pragma unroll
    for (int n = 0; n < 4; ++n)
#pragma unroll
      for (int r = 0; r < 4; ++r) {
        int row = m0 + wm * 64 + i * 16 + lq * 4 + r;
        int col = e0 + wn * 64 + n * 16 + lr;
        C[(size_t)row * 1024 + col] = acc[i][n][r];
      }
}

// =====================================================================
// k_gates: per-block redundant argmax(prev) -> si/ei; 16 gate rows/block.
// grid 32 x 256.
// =====================================================================
__global__ __launch_bounds__(256) void k_gates(
    const float* __restrict__ U,
    const float* __restrict__ Wih, const float* __restrict__ Whh,
    const float* __restrict__ bih, const float* __restrict__ bhh,
    const float* __restrict__ out, int step,
    float* __restrict__ ws) {
  __shared__ float ctx2[640];
  __shared__ float rv[256];
  __shared__ int   ri[256];
  __shared__ int   sei[2];
  int t = threadIdx.x;
  int b = blockIdx.x;

  if (step > 0) {
    int half = t >> 7, l = t & 127;
    const float* arr = out + (size_t)half * (NSTEP * MM) + (size_t)(step - 1) * MM;
    float bv = NEG_INF; int bi = 0;
    for (int i = l; i < MM; i += 128) {
      float v = arr[i];
      if (v > bv) { bv = v; bi = i; }
    }
    rv[t] = bv; ri[t] = bi;
    __syncthreads();
    for (int s = 64; s > 0; s >>= 1) {
      if (l < s) {
        float v2 = rv[t + s]; int i2 = ri[t + s];
        if (v2 > rv[t] || (v2 == rv[t] && i2 < ri[t])) { rv[t] = v2; ri[t] = i2; }
      }
      __syncthreads();
    }
    if (l == 0) sei[half] = ri[t];
    __syncthreads();
  } else {
    if (t == 0) { sei[0] = 0; sei[1] = MM - 1; }
    __syncthreads();
  }
  int si = sei[0], ei = sei[1];
  if (b == 0 && t == 0) { ((int*)ws)[WS_SIEI] = si; ((int*)ws)[WS_SIEI + 1] = ei; }

  ctx2[t]       = U[(size_t)si * 256 + t];
  ctx2[256 + t] = U[(size_t)ei * 256 + t];
  if (t < 128) ctx2[512 + t] = ws[WS_H0 + (step & 1) * 128 + t];
  __syncthreads();

  int row = b * 16 + (t >> 4), sub = t & 15;
  const float* wih = Wih + (size_t)row * 512;
  const float* whh = Whh + (size_t)row * 128;
  float acc = 0.f;
  int e0 = sub * 40;
#pragma unroll
  for (int e = e0; e < e0 + 40; e += 4) {
    float4 w = (e < 512) ? *(const float4*)&wih[e] : *(const float4*)&whh[e - 512];
    acc += w.x * ctx2[e] + w.y * ctx2[e + 1] + w.z * ctx2[e + 2] + w.w * ctx2[e + 3];
  }
#pragma unroll
  for (int off = 8; off > 0; off >>= 1) acc += __shfl_down(acc, off, 16);
  if (sub == 0) ws[WS_G + row] = acc + bih[row] + bhh[row];
}

// =====================================================================
// k_r: redundant h2/c2 from gates; blocks 0..15: r rows; block 16: logits +
// softmax + h/c writeback.  grid 17 x 256.
// =====================================================================
__global__ __launch_bounds__(256) void k_r(
    const float* __restrict__ U,
    const float* __restrict__ Wr_s, const float* __restrict__ br_s,
    const float* __restrict__ Wg_s, const float* __restrict__ bg_s,
    const float* __restrict__ Wr_e, const float* __restrict__ br_e,
    const float* __restrict__ Wg_e, const float* __restrict__ bg_e,
    int step, float* __restrict__ ws) {
  __shared__ float ctxR[640];
  __shared__ float gl[512];
  __shared__ float logit[4];
  int t = threadIdx.x, b = blockIdx.x;
  int si = ((const int*)ws)[WS_SIEI], ei = ((const int*)ws)[WS_SIEI + 1];

  gl[t] = ws[WS_G + t];
  gl[256 + t] = ws[WS_G + 256 + t];
  ctxR[128 + t] = U[(size_t)si * 256 + t];
  ctxR[384 + t] = U[(size_t)ei * 256 + t];
  __syncthreads();
  if (t < 128) {
    float ig = sigm(gl[t]);
    float fg = sigm(gl[128 + t]);
    float gg = tanhf(gl[256 + t]);
    float og = sigm(gl[384 + t]);
    float cp = ws[WS_C0 + (step & 1) * 128 + t];
    float c2 = fg * cp + ig * gg;
    float h2 = og * tanhf(c2);
    ctxR[t] = h2;
    if (b == 16) {
      ws[WS_C0 + ((step + 1) & 1) * 128 + t] = c2;
      ws[WS_H0 + ((step + 1) & 1) * 128 + t] = h2;
    }
  }
  __syncthreads();

  if (b < 16) {
    int rr = b * 16 + (t >> 4), sub = t & 15;
    int suf = rr >> 7, i = rr & 127;
    const float* Wr = suf ? Wr_e : Wr_s;
    const float* br = suf ? br_e : br_s;
    const float* w = Wr + (size_t)i * 640;
    float acc = 0.f;
    int e0 = sub * 40;
#pragma unroll
    for (int e = e0; e < e0 + 40; e += 4) {
      float4 wv = *(const float4*)&w[e];
      acc += wv.x * ctxR[e] + wv.y * ctxR[e + 1] + wv.z * ctxR[e + 2] + wv.w * ctxR[e + 3];
    }
#pragma unroll
    for (int off = 8; off > 0; off >>= 1) acc += __shfl_down(acc, off, 16);
    if (sub == 0) ws[(suf ? WS_RE : WS_RS) + i] = tanhf(acc + br[i]);
  } else {
    if (t < 64) {
      int which = t >> 4, sub = t & 15;
      const float* Wg = (which < 2) ? Wg_s : Wg_e;
      const float* bg = (which < 2) ? bg_s : bg_e;
      int i = which & 1;
      const float* w = Wg + (size_t)i * 640;
      float acc = 0.f;
      int e0 = sub * 40;
#pragma unroll
      for (int e = e0; e < e0 + 40; e += 4) {
        float4 wv = *(const float4*)&w[e];
        acc += wv.x * ctxR[e] + wv.y * ctxR[e + 1] + wv.z * ctxR[e + 2] + wv.w * ctxR[e + 3];
      }
#pragma unroll
      for (int off = 8; off > 0; off >>= 1) acc += __shfl_down(acc, off, 16);
      if (sub == 0) logit[which] = acc + bg[i];
    }
    __syncthreads();
    if (t == 0) {
      float a = logit[0], bb = logit[1], mx = fmaxf(a, bb);
      float ea = expf(a - mx), eb = expf(bb - mx), s = ea + eb;
      ws[WS_GS + 0] = ea / s; ws[WS_GS + 1] = eb / s;
      a = logit[2]; bb = logit[3]; mx = fmaxf(a, bb);
      ea = expf(a - mx); eb = expf(bb - mx); s = ea + eb;
      ws[WS_GS + 2] = ea / s; ws[WS_GS + 3] = eb / s;
    }
  }
}

// =====================================================================
// k_rt: rterm[row] = be + We_tail[row] . r_suf.  grid 64 x 256.
// =====================================================================
__global__ __launch_bounds__(256) void k_rt(
    const float* __restrict__ We_s, const float* __restrict__ be_s,
    const float* __restrict__ We_e, const float* __restrict__ be_e,
    float* __restrict__ ws) {
  __shared__ float rsh[256];
  int t = threadIdx.x, b = blockIdx.x;
  rsh[t] = ws[WS_RS + t];
  __syncthreads();
  int lrw = t >> 2, sub = t & 3;
  int row = b * 64 + lrw;
  int suf = row >> 11, ke = row & 2047;
  const float* We = suf ? We_e : We_s;
  const float* be = suf ? be_e : be_s;
  const float* w = We + (size_t)ke * 384 + 256;
  const float* r = rsh + suf * 128;
  float acc = 0.f;
  int e0 = sub * 32;
#pragma unroll
  for (int e = e0; e < e0 + 32; e += 4) {
    float4 wv = *(const float4*)&w[e];
    acc += wv.x * r[e] + wv.y * r[e + 1] + wv.z * r[e + 2] + wv.w * r[e + 3];
  }
#pragma unroll
  for (int off = 2; off > 0; off >>= 1) acc += __shfl_down(acc, off, 4);
  if (sub == 0) ws[WS_RT + row] = acc + be[ke];
}

// =====================================================================
// k_score3: FUSED ph1 (z0 maxout+mix) + ph2 (split-bf16 MFMA vs pre-split
// W2 from L2) + ph3.  16-row tiles, grid (256, 2) = 512 blocks = 2/CU.
// FROZEN (proven R7/R11).
// =====================================================================
__global__ __launch_bounds__(256) void k_score3(
    const float* __restrict__ b2_a, const float* __restrict__ W3_a, const float* __restrict__ b3_a,
    const float* __restrict__ b2_b, const float* __restrict__ W3_b, const float* __restrict__ b3_b,
    float* __restrict__ out_a, float* __restrict__ out_b,
    float* __restrict__ ws) {
  __shared__ float rtm[2048];
  __shared__ float m1f[16][132];
  __shared__ float m2f[16][132];
  __shared__ float sj[16][8];

  const float* z0 = ws + WS_Z0;
  const unsigned short* w2base = (const unsigned short*)(ws + WS_W2S);

  int t = threadIdx.x;
  int suf = blockIdx.y;
  int m0 = blockIdx.x * 16;
  const float* b2 = suf ? b2_b : b2_a;
  const float* W3 = suf ? W3_b : W3_a;
  const float* b3 = suf ? b3_b : b3_a;
  float*     outp = suf ? out_b : out_a;
  const unsigned short* w2h = w2base + (size_t)suf * 131072;
  const unsigned short* w2l = w2base + W2SPLIT_N + (size_t)suf * 131072;

  for (int l = t; l < 2048; l += 256) rtm[l] = ws[WS_RT + suf * 2048 + l];
  float g0 = ws[WS_GS + suf * 2 + 0];
  float g1 = ws[WS_GS + suf * 2 + 1];
  __syncthreads();

  // ---- phase 1: maxout over p, mixture over k -> m1f (16 rows) ----
  {
    int row = t >> 4, c8 = (t & 15) * 8;
    const float* p0 = z0 + ((size_t)(suf * 2 + 0) * MM + m0 + row) * 1024 + c8;
    const float* p1 = z0 + ((size_t)(suf * 2 + 1) * MM + m0 + row) * 1024 + c8;
    float4 mxa0 = {NEG_INF, NEG_INF, NEG_INF, NEG_INF}, mxb0 = mxa0;
    float4 mxa1 = mxa0, mxb1 = mxa0;
#pragma unroll
    for (int pp = 0; pp < 8; ++pp) {
      float4 va0 = *(const float4*)&p0[pp * 128];
      float4 vb0 = *(const float4*)&p0[pp * 128 + 4];
      float4 ra0 = *(const float4*)&rtm[pp * 128 + c8];
      float4 rb0 = *(const float4*)&rtm[pp * 128 + c8 + 4];
      mxa0.x = fmaxf(mxa0.x, va0.x + ra0.x); mxa0.y = fmaxf(mxa0.y, va0.y + ra0.y);
      mxa0.z = fmaxf(mxa0.z, va0.z + ra0.z); mxa0.w = fmaxf(mxa0.w, va0.w + ra0.w);
      mxb0.x = fmaxf(mxb0.x, vb0.x + rb0.x); mxb0.y = fmaxf(mxb0.y, vb0.y + rb0.y);
      mxb0.z = fmaxf(mxb0.z, vb0.z + rb0.z); mxb0.w = fmaxf(mxb0.w, vb0.w + rb0.w);
      float4 va1 = *(const float4*)&p1[pp * 128];
      float4 vb1 = *(const float4*)&p1[pp * 128 + 4];
      float4 ra1 = *(const float4*)&rtm[1024 + pp * 128 + c8];
      float4 rb1 = *(const float4*)&rtm[1024 + pp * 128 + c8 + 4];
      mxa1.x = fmaxf(mxa1.x, va1.x + ra1.x); mxa1.y = fmaxf(mxa1.y, va1.y + ra1.y);
      mxa1.z = fmaxf(mxa1.z, va1.z + ra1.z); mxa1.w = fmaxf(mxa1.w, va1.w + ra1.w);
      mxb1.x = fmaxf(mxb1.x, vb1.x + rb1.x); mxb1.y = fmaxf(mxb1.y, vb1.y + rb1.y);
      mxb1.z = fmaxf(mxb1.z, vb1.z + rb1.z); mxb1.w = fmaxf(mxb1.w, vb1.w + rb1.w);
    }
    float4 o0 = {g0 * mxa0.x + g1 * mxa1.x, g0 * mxa0.y + g1 * mxa1.y,
                 g0 * mxa0.z + g1 * mxa1.z, g0 * mxa0.w + g1 * mxa1.w};
    float4 o1 = {g0 * mxb0.x + g1 * mxb1.x, g0 * mxb0.y + g1 * mxb1.y,
                 g0 * mxb0.z + g1 * mxb1.z, g0 * mxb0.w + g1 * mxb1.w};
    *(float4*)&m1f[row][c8] = o0;
    *(float4*)&m1f[row][c8 + 4] = o1;
  }
  __syncthreads();

  // ---- A fragments: split m1 rows hi/lo in registers ----
  int lane = t & 63, wid = t >> 6;
  int wcol = wid * 32;
  int lr = lane & 15, lk = (lane >> 4) * 8, lq = lane >> 4;
  bf16x8 ah[4], al[4];
#pragma unroll
  for (int kk = 0; kk < 4; ++kk) {
    float4 x0 = *(const float4*)&m1f[lr][kk * 32 + lk];
    float4 x1 = *(const float4*)&m1f[lr][kk * 32 + lk + 4];
    u16x4 h0, l0, h1, l1;
    split4(x0, &h0, &l0); split4(x1, &h1, &l1);
    bf16x8 a, b;
#pragma unroll
    for (int j = 0; j < 4; ++j) { a[j] = (short)h0[j]; a[4 + j] = (short)h1[j]; }
#pragma unroll
    for (int j = 0; j < 4; ++j) { b[j] = (short)l0[j]; b[4 + j] = (short)l1[j]; }
    ah[kk] = a; al[kk] = b;
  }

  // ---- phase 2: split-bf16 MFMA, B from global L2, maxout over sp ----
  float m2x[2][4];
#pragma unroll
  for (int nt = 0; nt < 2; ++nt)
#pragma unroll
    for (int r = 0; r < 4; ++r) m2x[nt][r] = NEG_INF;

  for (int sp = 0; sp < 8; ++sp) {
    f32x4 zz = {0.f, 0.f, 0.f, 0.f};
    f32x4 acc[2][2] = {{zz, zz}, {zz, zz}};
#pragma unroll
    for (int kk = 0; kk < 4; ++kk)
#pragma unroll
      for (int nt = 0; nt < 2; ++nt) {
        size_t boff = (size_t)(sp * 128 + wcol + nt * 16 + lr) * 128 + kk * 32 + lk;
        bf16x8 bhf = *(const bf16x8*)&w2h[boff];
        bf16x8 blf = *(const bf16x8*)&w2l[boff];
        int par = kk & 1;
        acc[nt][par] = __builtin_amdgcn_mfma_f32_16x16x32_bf16(ah[kk], bhf, acc[nt][par], 0, 0, 0);
        acc[nt][par] = __builtin_amdgcn_mfma_f32_16x16x32_bf16(ah[kk], blf, acc[nt][par], 0, 0, 0);
        acc[nt][par] = __builtin_amdgcn_mfma_f32_16x16x32_bf16(al[kk], bhf, acc[nt][par], 0, 0, 0);
      }
#pragma unroll
    for (int nt = 0; nt < 2; ++nt) {
      float bias = b2[sp * 128 + wcol + nt * 16 + lr];
#pragma unroll
      for (int r = 0; r < 4; ++r)
        m2x[nt][r] = fmaxf(m2x[nt][r], acc[nt][0][r] + acc[nt][1][r] + bias);
    }
  }
#pragma unroll
  for (int nt = 0; nt < 2; ++nt)
#pragma unroll
    for (int r = 0; r < 4; ++r)
      m2f[lq * 4 + r][wcol + nt * 16 + lr] = m2x[nt][r];
  __syncthreads();

  // ---- phase 3: [m1|m2] @ W3^T + b3, max over 8 ----
  if (t < 128) {
    int row = t & 15, jp = t >> 4;
    const float* w3 = W3 + jp * 256;
    float acc = b3[jp];
    for (int f = 0; f < 128; f += 4) {
      float4 w = *(const float4*)&w3[f];
      acc += w.x * m1f[row][f] + w.y * m1f[row][f + 1] + w.z * m1f[row][f + 2] + w.w * m1f[row][f + 3];
    }
    for (int f = 0; f < 128; f += 4) {
      float4 w = *(const float4*)&w3[128 + f];
      acc += w.x * m2f[row][f] + w.y * m2f[row][f + 1] + w.z * m2f[row][f + 2] + w.w * m2f[row][f + 3];
    }
    sj[row][jp] = acc;
  }
  __syncthreads();
  if (t < 16) {
    float mx = sj[t][0];
#pragma unroll
    for (int j = 1; j < 8; ++j) mx = fmaxf(mx, sj[t][j]);
    outp[m0 + t] = mx;
  }
}

// =====================================================================
// slow fallback (tiny ws)
// =====================================================================
__global__ void k_score_slow(
    const float* __restrict__ U,
    const float* __restrict__ We_a, const float* __restrict__ We_b,
    const float* __restrict__ W2_a, const float* __restrict__ b2_a,
    const float* __restrict__ W3_a, const float* __restrict__ b3_a,
    const float* __restrict__ W2_b, const float* __restrict__ b2_b,
    const float* __restrict__ W3_b, const float* __restrict__ b3_b,
    float* __restrict__ out_a, float* __restrict__ out_b,
    const float* __restrict__ ws) {
  __shared__ float u[256];
  __shared__ float m1s[128];
  __shared__ float m2v[1024];
  __shared__ float m2s[128];
  __shared__ float sjs[8];
  int t = threadIdx.x;
  int m = blockIdx.x;
  int suf = blockIdx.y;
  const float* We = suf ? We_b : We_a;
  const float* W2 = suf ? W2_b : W2_a;
  const float* b2 = suf ? b2_b : b2_a;
  const float* W3 = suf ? W3_b : W3_a;
  const float* b3 = suf ? b3_b : b3_a;
  float*     outp = suf ? out_b : out_a;
  float g0 = ws[WS_GS + suf * 2 + 0];
  float g1 = ws[WS_GS + suf * 2 + 1];
  const float* rt = ws + WS_RT + suf * 2048;

  u[t] = U[(size_t)m * 256 + t];
  __syncthreads();
  if (t < 128) {
    float mx[2] = {NEG_INF, NEG_INF};
    for (int k = 0; k < 2; ++k)
      for (int pp = 0; pp < 8; ++pp) {
        int e = k * 1024 + pp * 128 + t;
        const float* w = We + (size_t)e * 384;
        float acc = rt[e];
        for (int f = 0; f < 256; f += 4) {
          float4 wv = *(const float4*)&w[f];
          acc += wv.x * u[f] + wv.y * u[f + 1] + wv.z * u[f + 2] + wv.w * u[f + 3];
        }
        mx[k] = fmaxf(mx[k], acc);
      }
    m1s[t] = g0 * mx[0] + g1 * mx[1];
  }
  __syncthreads();
  for (int e = t; e < 1024; e += 256) {
    const float* w = W2 + (size_t)e * 128;
    float acc = b2[e];
    for (int f = 0; f < 128; f += 4) {
      float4 wv = *(const float4*)&w[f];
      acc += wv.x * m1s[f] + wv.y * m1s[f + 1] + wv.z * m1s[f + 2] + wv.w * m1s[f + 3];
    }
    m2v[e] = acc;
  }
  __syncthreads();
  if (t < 128) {
    float mx = NEG_INF;
    for (int pp = 0; pp < 8; ++pp) mx = fmaxf(mx, m2v[pp * 128 + t]);
    m2s[t] = mx;
  }
  __syncthreads();
  if (t < 8) {
    const float* w3 = W3 + t * 256;
    float acc = b3[t];
    for (int f = 0; f < 128; ++f) acc += w3[f] * m1s[f];
    for (int f = 0; f < 128; ++f) acc += w3[128 + f] * m2s[f];
    sjs[t] = acc;
  }
  __syncthreads();
  if (t == 0) {
    float mx = sjs[0];
    for (int j = 1; j < 8; ++j) mx = fmaxf(mx, sjs[j]);
    outp[m] = mx;
  }
}

// =====================================================================
extern "C" void kernel_launch(void* const* d_in, const int* in_sizes, int n_in,
                              void* d_out, int out_size, void* d_ws, size_t ws_size,
                              hipStream_t stream) {
  const float* U    = (const float*)d_in[0];
  const float* Wih  = (const float*)d_in[1];
  const float* Whh  = (const float*)d_in[2];
  const float* bih  = (const float*)d_in[3];
  const float* bhh  = (const float*)d_in[4];
  const float* Wr_s = (const float*)d_in[5];
  const float* br_s = (const float*)d_in[6];
  const float* Wg_s = (const float*)d_in[7];
  const float* bg_s = (const float*)d_in[8];
  const float* We_s = (const float*)d_in[9];
  const float* be_s = (const float*)d_in[10];
  const float* W2_s = (const float*)d_in[11];
  const float* b2_s = (const float*)d_in[12];
  const float* W3_s = (const float*)d_in[13];
  const float* b3_s = (const float*)d_in[14];
  const float* Wr_e = (const float*)d_in[15];
  const float* br_e = (const float*)d_in[16];
  const float* Wg_e = (const float*)d_in[17];
  const float* bg_e = (const float*)d_in[18];
  const float* We_e = (const float*)d_in[19];
  const float* be_e = (const float*)d_in[20];
  const float* W2_e = (const float*)d_in[21];
  const float* b2_e = (const float*)d_in[22];
  const float* W3_e = (const float*)d_in[23];
  const float* b3_e = (const float*)d_in[24];
  float* out = (float*)d_out;
  float* ws  = (float*)d_ws;

  int fast4 = (ws_size >= (size_t)WS_END4 * 4);
  int fast2 = (ws_size >= (size_t)WS_END2 * 4);

  k_init<<<1, 128, 0, stream>>>(ws);
  if (fast2) {
    k_prep<<<768, 256, 0, stream>>>(W2_s, W2_e, U, We_s, We_e, fast4, ws);
    if (fast4) {
      k_z0m2<<<dim3(32, 8, 4), 256, 0, stream>>>(ws);
    } else {
      k_z0m<<<dim3(32, 8, 4), 256, 0, stream>>>(U, We_s, We_e, ws);
    }
  }

  for (int step = 0; step < NSTEP; ++step) {
    k_gates<<<32, 256, 0, stream>>>(U, Wih, Whh, bih, bhh, out, step, ws);
    k_r<<<17, 256, 0, stream>>>(U, Wr_s, br_s, Wg_s, bg_s,
                                Wr_e, br_e, Wg_e, bg_e, step, ws);
    k_rt<<<64, 256, 0, stream>>>(We_s, be_s, We_e, be_e, ws);

    float* out_s = out + (size_t)step * MM;
    float* out_e = out + (size_t)NSTEP * MM + (size_t)step * MM;

    if (fast2) {
      k_score3<<<dim3(256, 2), 256, 0, stream>>>(
          b2_s, W3_s, b3_s, b2_e, W3_e, b3_e, out_s, out_e, ws);
    } else {
      k_score_slow<<<dim3(MM, 2), 256, 0, stream>>>(
          U, We_s, We_e,
          W2_s, b2_s, W3_s, b3_s,
          W2_e, b2_e, W3_e, b3_e,
          out_s, out_e, ws);
    }
  }
}

// Round 14
// 286.751 us; speedup vs baseline: 1.6601x; 1.0168x over previous
//
#include <hip/hip_runtime.h>
#include <math.h>

// ---------------- problem constants ----------------
#define DD   128
#define MM   4096
#define NSTEP 4
#define NEG_INF (-3.4e38f)

// ---------------- ws float-offset layout ----------------
#define WS_H0   0          // h slots [2][128]
#define WS_C0   256        // c slots [2][128]
#define WS_G    512        // 512 gate preacts
#define WS_RS   1024       // 128
#define WS_RE   1152       // 128
#define WS_GS   1280       // 4
#define WS_SIEI 1284       // 2 ints
#define WS_RT   2048       // 4096
#define WS_Z0   8192       // f32 z0 [suf*2+k][4096][1024] = 16,777,216 floats
#define WS_W2S  (8192 + 16777216)       // W2 split: 2x262144 ushort = 262,144 floats
#define WS_USP  (WS_W2S + 262144)       // U split: 2x1,048,576 ushort = 1,048,576 floats
#define WS_WESP (WS_USP + 1048576)      // We split: 2x1,048,576 ushort = 1,048,576 floats
#define WS_END2 (WS_W2S + 262144)       // fast2: 68,190,208 B  (proven available)
#define WS_END4 (WS_WESP + 1048576)     // fast4: 76,578,816 B  (confirmed: ws ~256 MB)
#define W2SPLIT_N 262144
#define USPLIT_N  1048576
#define WESPLIT_N 1048576

typedef __attribute__((ext_vector_type(8))) short bf16x8;
typedef __attribute__((ext_vector_type(4))) float f32x4;
typedef __attribute__((ext_vector_type(4))) unsigned short u16x4;

static __device__ __forceinline__ unsigned short f2b(float x) {
  unsigned u = __float_as_uint(x);
  unsigned r = (u + 0x7fffu + ((u >> 16) & 1u)) >> 16;   // RNE
  return (unsigned short)r;
}
static __device__ __forceinline__ float b2f(unsigned short h) {
  return __uint_as_float(((unsigned)h) << 16);
}
static __device__ __forceinline__ void split4(float4 v, u16x4* h, u16x4* l) {
  unsigned short h0 = f2b(v.x), h1 = f2b(v.y), h2 = f2b(v.z), h3 = f2b(v.w);
  u16x4 hh = {h0, h1, h2, h3};
  u16x4 ll = {f2b(v.x - b2f(h0)), f2b(v.y - b2f(h1)),
              f2b(v.z - b2f(h2)), f2b(v.w - b2f(h3))};
  *h = hh; *l = ll;
}
static __device__ __forceinline__ float sigm(float x) {
  return 1.f / (1.f + expf(-x));
}

// =====================================================================
// init (non-fast fallback path only; fast path folds this into k_prep)
// =====================================================================
__global__ void k_init(float* __restrict__ ws) {
  int t = threadIdx.x;
  if (t < 128) { ws[WS_H0 + t] = 0.f; ws[WS_C0 + t] = 0.f; }
}

// =====================================================================
// prep (merged): h/c init (block 0) + split W2 hi/lo; (fast4) split U and
// We-head hi/lo.  First dispatch of the launch — h/c slot 0 is consumed
// only by k_r at step 0, several dispatches later.
// =====================================================================
__global__ void k_prep(const float* __restrict__ W2_s,
                       const float* __restrict__ W2_e,
                       const float* __restrict__ U,
                       const float* __restrict__ We_s, const float* __restrict__ We_e,
                       int do4, float* __restrict__ ws) {
  if (blockIdx.x == 0 && threadIdx.x < 128) {
    ws[WS_H0 + threadIdx.x] = 0.f;
    ws[WS_C0 + threadIdx.x] = 0.f;
  }
  unsigned short* w2h = (unsigned short*)(ws + WS_W2S);
  unsigned short* w2l = w2h + W2SPLIT_N;
  unsigned short* uh = (unsigned short*)(ws + WS_USP);
  unsigned short* ul = uh + USPLIT_N;
  unsigned short* wh = (unsigned short*)(ws + WS_WESP);
  unsigned short* wl = wh + WESPLIT_N;
  int total = do4 ? (W2SPLIT_N + USPLIT_N + WESPLIT_N) : W2SPLIT_N;
  for (int i = blockIdx.x * blockDim.x + threadIdx.x; i < total;
       i += gridDim.x * blockDim.x) {
    if (i < W2SPLIT_N) {
      int suf = i >> 17;
      int rem = i & 131071;
      float v = (suf ? W2_e : W2_s)[rem];
      unsigned short h = f2b(v);
      w2h[i] = h; w2l[i] = f2b(v - b2f(h));
    } else if (i < W2SPLIT_N + USPLIT_N) {
      int j = i - W2SPLIT_N;
      float v = U[j];
      unsigned short h = f2b(v);
      uh[j] = h; ul[j] = f2b(v - b2f(h));
    } else {
      int j = i - W2SPLIT_N - USPLIT_N;
      int z = j >> 18;
      int rem = j & 262143;
      int e = rem >> 8, f = rem & 255;
      int suf = z >> 1, k = z & 1;
      const float* We = suf ? We_e : We_s;
      float v = We[((size_t)k * 1024 + e) * 384 + f];
      unsigned short h = f2b(v);
      wh[j] = h; wl[j] = f2b(v - b2f(h));
    }
  }
}

// =====================================================================
// k_z0m2 (fast4): Z0 GEMM from PRE-SPLIT bf16 (staging = pure copy)
// grid (32, 8, 4), 256 thr, tile 128x128, BK=32
// =====================================================================
__global__ __launch_bounds__(256) void k_z0m2(float* __restrict__ ws) {
  __shared__ unsigned short Ah[128][40];
  __shared__ unsigned short Al[128][40];
  __shared__ unsigned short Bh[128][40];
  __shared__ unsigned short Bl[128][40];
  float* z0 = ws + WS_Z0;
  const unsigned short* uh = (const unsigned short*)(ws + WS_USP);
  const unsigned short* ul = uh + USPLIT_N;
  const unsigned short* wh = (const unsigned short*)(ws + WS_WESP);
  const unsigned short* wl = wh + WESPLIT_N;

  int t = threadIdx.x;
  int lane = t & 63, wid = t >> 6;
  int wm = wid >> 1, wn = wid & 1;
  int lr = lane & 15, lk = (lane >> 4) * 8, lq = lane >> 4;
  int m0 = blockIdx.x * 128, e0 = blockIdx.y * 128;
  int z = blockIdx.z;
  const unsigned short* bh0 = wh + (size_t)z * 262144;
  const unsigned short* bl0 = wl + (size_t)z * 262144;

  f32x4 acc[4][4];
  f32x4 zz = {0.f, 0.f, 0.f, 0.f};
#pragma unroll
  for (int i = 0; i < 4; ++i)
#pragma unroll
    for (int n = 0; n < 4; ++n) acc[i][n] = zz;

  for (int kc = 0; kc < 8; ++kc) {
    int k0 = kc * 32;
    __syncthreads();
#pragma unroll
    for (int it = 0; it < 2; ++it) {
      int idx = t + it * 256;            // 512 tasks: row, 8-elem group
      int row = idx >> 2, q8 = (idx & 3) * 8;
      size_t goff = (size_t)(m0 + row) * 256 + k0 + q8;
      *(uint4*)&Ah[row][q8] = *(const uint4*)&uh[goff];
      *(uint4*)&Al[row][q8] = *(const uint4*)&ul[goff];
      size_t boff = (size_t)(e0 + row) * 256 + k0 + q8;
      *(uint4*)&Bh[row][q8] = *(const uint4*)&bh0[boff];
      *(uint4*)&Bl[row][q8] = *(const uint4*)&bl0[boff];
    }
    __syncthreads();
    bf16x8 ah[4], al[4], bh[4], bl[4];
#pragma unroll
    for (int i = 0; i < 4; ++i) {
      ah[i] = *(bf16x8*)&Ah[wm * 64 + i * 16 + lr][lk];
      al[i] = *(bf16x8*)&Al[wm * 64 + i * 16 + lr][lk];
    }
#pragma unroll
    for (int n = 0; n < 4; ++n) {
      bh[n] = *(bf16x8*)&Bh[wn * 64 + n * 16 + lr][lk];
      bl[n] = *(bf16x8*)&Bl[wn * 64 + n * 16 + lr][lk];
    }
#pragma unroll
    for (int i = 0; i < 4; ++i)
#pragma unroll
      for (int n = 0; n < 4; ++n) {
        acc[i][n] = __builtin_amdgcn_mfma_f32_16x16x32_bf16(ah[i], bh[n], acc[i][n], 0, 0, 0);
        acc[i][n] = __builtin_amdgcn_mfma_f32_16x16x32_bf16(ah[i], bl[n], acc[i][n], 0, 0, 0);
        acc[i][n] = __builtin_amdgcn_mfma_f32_16x16x32_bf16(al[i], bh[n], acc[i][n], 0, 0, 0);
      }
  }

  float* C = z0 + (size_t)z * MM * 1024;
#pragma unroll
  for (int i = 0; i < 4; ++i)
#pragma unroll
    for (int n = 0; n < 4; ++n)
#pragma unroll
      for (int r = 0; r < 4; ++r) {
        int row = m0 + wm * 64 + i * 16 + lq * 4 + r;
        int col = e0 + wn * 64 + n * 16 + lr;
        C[(size_t)row * 1024 + col] = acc[i][n][r];
      }
}

// =====================================================================
// k_z0m (fast2 fallback): inline-split Z0 GEMM
// =====================================================================
__global__ __launch_bounds__(256) void k_z0m(
    const float* __restrict__ U,
    const float* __restrict__ We_s, const float* __restrict__ We_e,
    float* __restrict__ ws) {
  __shared__ unsigned short Ah[128][40];
  __shared__ unsigned short Al[128][40];
  __shared__ unsigned short Bh[128][40];
  __shared__ unsigned short Bl[128][40];
  float* z0 = ws + WS_Z0;

  int t = threadIdx.x;
  int lane = t & 63, wid = t >> 6;
  int wm = wid >> 1, wn = wid & 1;
  int lr = lane & 15, lk = (lane >> 4) * 8, lq = lane >> 4;
  int m0 = blockIdx.x * 128, e0 = blockIdx.y * 128;
  int z = blockIdx.z;
  int suf = z >> 1, k = z & 1;
  const float* Wep = (suf ? We_e : We_s) + (size_t)k * 1024 * 384;

  f32x4 acc[4][4];
  f32x4 zz = {0.f, 0.f, 0.f, 0.f};
#pragma unroll
  for (int i = 0; i < 4; ++i)
#pragma unroll
    for (int n = 0; n < 4; ++n) acc[i][n] = zz;

  for (int kc = 0; kc < 8; ++kc) {
    int k0 = kc * 32;
    __syncthreads();
#pragma unroll
    for (int it = 0; it < 4; ++it) {
      int idx = t + it * 256;
      int row = idx >> 3, q = idx & 7;
      float4 va = *(const float4*)&U[(size_t)(m0 + row) * 256 + k0 + q * 4];
      u16x4 h, l; split4(va, &h, &l);
      *(u16x4*)&Ah[row][q * 4] = h;
      *(u16x4*)&Al[row][q * 4] = l;
      float4 vb = *(const float4*)&Wep[(size_t)(e0 + row) * 384 + k0 + q * 4];
      split4(vb, &h, &l);
      *(u16x4*)&Bh[row][q * 4] = h;
      *(u16x4*)&Bl[row][q * 4] = l;
    }
    __syncthreads();
    bf16x8 ah[4], al[4], bh[4], bl[4];
#pragma unroll
    for (int i = 0; i < 4; ++i) {
      ah[i] = *(bf16x8*)&Ah[wm * 64 + i * 16 + lr][lk];
      al[i] = *(bf16x8*)&Al[wm * 64 + i * 16 + lr][lk];
    }
#pragma unroll
    for (int n = 0; n < 4; ++n) {
      bh[n] = *(bf16x8*)&Bh[wn * 64 + n * 16 + lr][lk];
      bl[n] = *(bf16x8*)&Bl[wn * 64 + n * 16 + lr][lk];
    }
#pragma unroll
    for (int i = 0; i < 4; ++i)
#pragma unroll
      for (int n = 0; n < 4; ++n) {
        acc[i][n] = __builtin_amdgcn_mfma_f32_16x16x32_bf16(ah[i], bh[n], acc[i][n], 0, 0, 0);
        acc[i][n] = __builtin_amdgcn_mfma_f32_16x16x32_bf16(ah[i], bl[n], acc[i][n], 0, 0, 0);
        acc[i][n] = __builtin_amdgcn_mfma_f32_16x16x32_bf16(al[i], bh[n], acc[i][n], 0, 0, 0);
      }
  }

  float* C = z0 + (size_t)z * MM * 1024;
#pragma unroll
  for (int i = 0; i < 4; ++i)
#pragma unroll
    for (int n = 0; n < 4; ++n)
#pragma unroll
      for (int r = 0; r < 4; ++r) {
        int row = m0 + wm * 64 + i * 16 + lq * 4 + r;
        int col = e0 + wn * 64 + n * 16 + lr;
        C[(size_t)row * 1024 + col] = acc[i][n][r];
      }
}

// =====================================================================
// k_gates: per-block redundant argmax(prev) -> si/ei; 16 gate rows/block.
// grid 32 x 256.
// =====================================================================
__global__ __launch_bounds__(256) void k_gates(
    const float* __restrict__ U,
    const float* __restrict__ Wih, const float* __restrict__ Whh,
    const float* __restrict__ bih, const float* __restrict__ bhh,
    const float* __restrict__ out, int step,
    float* __restrict__ ws) {
  __shared__ float ctx2[640];
  __shared__ float rv[256];
  __shared__ int   ri[256];
  __shared__ int   sei[2];
  int t = threadIdx.x;
  int b = blockIdx.x;

  if (step > 0) {
    int half = t >> 7, l = t & 127;
    const float* arr = out + (size_t)half * (NSTEP * MM) + (size_t)(step - 1) * MM;
    float bv = NEG_INF; int bi = 0;
    for (int i = l; i < MM; i += 128) {
      float v = arr[i];
      if (v > bv) { bv = v; bi = i; }
    }
    rv[t] = bv; ri[t] = bi;
    __syncthreads();
    for (int s = 64; s > 0; s >>= 1) {
      if (l < s) {
        float v2 = rv[t + s]; int i2 = ri[t + s];
        if (v2 > rv[t] || (v2 == rv[t] && i2 < ri[t])) { rv[t] = v2; ri[t] = i2; }
      }
      __syncthreads();
    }
    if (l == 0) sei[half] = ri[t];
    __syncthreads();
  } else {
    if (t == 0) { sei[0] = 0; sei[1] = MM - 1; }
    __syncthreads();
  }
  int si = sei[0], ei = sei[1];
  if (b == 0 && t == 0) { ((int*)ws)[WS_SIEI] = si; ((int*)ws)[WS_SIEI + 1] = ei; }

  ctx2[t]       = U[(size_t)si * 256 + t];
  ctx2[256 + t] = U[(size_t)ei * 256 + t];
  if (t < 128) ctx2[512 + t] = ws[WS_H0 + (step & 1) * 128 + t];
  __syncthreads();

  int row = b * 16 + (t >> 4), sub = t & 15;
  const float* wih = Wih + (size_t)row * 512;
  const float* whh = Whh + (size_t)row * 128;
  float acc = 0.f;
  int e0 = sub * 40;
#pragma unroll
  for (int e = e0; e < e0 + 40; e += 4) {
    float4 w = (e < 512) ? *(const float4*)&wih[e] : *(const float4*)&whh[e - 512];
    acc += w.x * ctx2[e] + w.y * ctx2[e + 1] + w.z * ctx2[e + 2] + w.w * ctx2[e + 3];
  }
#pragma unroll
  for (int off = 8; off > 0; off >>= 1) acc += __shfl_down(acc, off, 16);
  if (sub == 0) ws[WS_G + row] = acc + bih[row] + bhh[row];
}

// =====================================================================
// k_r: redundant h2/c2 from gates; blocks 0..15: r rows; block 16: logits +
// softmax + h/c writeback.  grid 17 x 256.
// =====================================================================
__global__ __launch_bounds__(256) void k_r(
    const float* __restrict__ U,
    const float* __restrict__ Wr_s, const float* __restrict__ br_s,
    const float* __restrict__ Wg_s, const float* __restrict__ bg_s,
    const float* __restrict__ Wr_e, const float* __restrict__ br_e,
    const float* __restrict__ Wg_e, const float* __restrict__ bg_e,
    int step, float* __restrict__ ws) {
  __shared__ float ctxR[640];
  __shared__ float gl[512];
  __shared__ float logit[4];
  int t = threadIdx.x, b = blockIdx.x;
  int si = ((const int*)ws)[WS_SIEI], ei = ((const int*)ws)[WS_SIEI + 1];

  gl[t] = ws[WS_G + t];
  gl[256 + t] = ws[WS_G + 256 + t];
  ctxR[128 + t] = U[(size_t)si * 256 + t];
  ctxR[384 + t] = U[(size_t)ei * 256 + t];
  __syncthreads();
  if (t < 128) {
    float ig = sigm(gl[t]);
    float fg = sigm(gl[128 + t]);
    float gg = tanhf(gl[256 + t]);
    float og = sigm(gl[384 + t]);
    float cp = ws[WS_C0 + (step & 1) * 128 + t];
    float c2 = fg * cp + ig * gg;
    float h2 = og * tanhf(c2);
    ctxR[t] = h2;
    if (b == 16) {
      ws[WS_C0 + ((step + 1) & 1) * 128 + t] = c2;
      ws[WS_H0 + ((step + 1) & 1) * 128 + t] = h2;
    }
  }
  __syncthreads();

  if (b < 16) {
    int rr = b * 16 + (t >> 4), sub = t & 15;
    int suf = rr >> 7, i = rr & 127;
    const float* Wr = suf ? Wr_e : Wr_s;
    const float* br = suf ? br_e : br_s;
    const float* w = Wr + (size_t)i * 640;
    float acc = 0.f;
    int e0 = sub * 40;
#pragma unroll
    for (int e = e0; e < e0 + 40; e += 4) {
      float4 wv = *(const float4*)&w[e];
      acc += wv.x * ctxR[e] + wv.y * ctxR[e + 1] + wv.z * ctxR[e + 2] + wv.w * ctxR[e + 3];
    }
#pragma unroll
    for (int off = 8; off > 0; off >>= 1) acc += __shfl_down(acc, off, 16);
    if (sub == 0) ws[(suf ? WS_RE : WS_RS) + i] = tanhf(acc + br[i]);
  } else {
    if (t < 64) {
      int which = t >> 4, sub = t & 15;
      const float* Wg = (which < 2) ? Wg_s : Wg_e;
      const float* bg = (which < 2) ? bg_s : bg_e;
      int i = which & 1;
      const float* w = Wg + (size_t)i * 640;
      float acc = 0.f;
      int e0 = sub * 40;
#pragma unroll
      for (int e = e0; e < e0 + 40; e += 4) {
        float4 wv = *(const float4*)&w[e];
        acc += wv.x * ctxR[e] + wv.y * ctxR[e + 1] + wv.z * ctxR[e + 2] + wv.w * ctxR[e + 3];
      }
#pragma unroll
      for (int off = 8; off > 0; off >>= 1) acc += __shfl_down(acc, off, 16);
      if (sub == 0) logit[which] = acc + bg[i];
    }
    __syncthreads();
    if (t == 0) {
      float a = logit[0], bb = logit[1], mx = fmaxf(a, bb);
      float ea = expf(a - mx), eb = expf(bb - mx), s = ea + eb;
      ws[WS_GS + 0] = ea / s; ws[WS_GS + 1] = eb / s;
      a = logit[2]; bb = logit[3]; mx = fmaxf(a, bb);
      ea = expf(a - mx); eb = expf(bb - mx); s = ea + eb;
      ws[WS_GS + 2] = ea / s; ws[WS_GS + 3] = eb / s;
    }
  }
}

// =====================================================================
// k_rt: rterm[row] = be + We_tail[row] . r_suf.  grid 64 x 256.
// =====================================================================
__global__ __launch_bounds__(256) void k_rt(
    const float* __restrict__ We_s, const float* __restrict__ be_s,
    const float* __restrict__ We_e, const float* __restrict__ be_e,
    float* __restrict__ ws) {
  __shared__ float rsh[256];
  int t = threadIdx.x, b = blockIdx.x;
  rsh[t] = ws[WS_RS + t];
  __syncthreads();
  int lrw = t >> 2, sub = t & 3;
  int row = b * 64 + lrw;
  int suf = row >> 11, ke = row & 2047;
  const float* We = suf ? We_e : We_s;
  const float* be = suf ? be_e : be_s;
  const float* w = We + (size_t)ke * 384 + 256;
  const float* r = rsh + suf * 128;
  float acc = 0.f;
  int e0 = sub * 32;
#pragma unroll
  for (int e = e0; e < e0 + 32; e += 4) {
    float4 wv = *(const float4*)&w[e];
    acc += wv.x * r[e] + wv.y * r[e + 1] + wv.z * r[e + 2] + wv.w * r[e + 3];
  }
#pragma unroll
  for (int off = 2; off > 0; off >>= 1) acc += __shfl_down(acc, off, 4);
  if (sub == 0) ws[WS_RT + row] = acc + be[ke];
}

// =====================================================================
// k_score3: FUSED ph1 (z0 maxout+mix) + ph2 (split-bf16 MFMA vs pre-split
// W2 from L2) + ph3.  16-row tiles, grid (256, 2) = 512 blocks = 2/CU.
// FROZEN (proven R7/R11/R13).
// =====================================================================
__global__ __launch_bounds__(256) void k_score3(
    const float* __restrict__ b2_a, const float* __restrict__ W3_a, const float* __restrict__ b3_a,
    const float* __restrict__ b2_b, const float* __restrict__ W3_b, const float* __restrict__ b3_b,
    float* __restrict__ out_a, float* __restrict__ out_b,
    float* __restrict__ ws) {
  __shared__ float rtm[2048];
  __shared__ float m1f[16][132];
  __shared__ float m2f[16][132];
  __shared__ float sj[16][8];

  const float* z0 = ws + WS_Z0;
  const unsigned short* w2base = (const unsigned short*)(ws + WS_W2S);

  int t = threadIdx.x;
  int suf = blockIdx.y;
  int m0 = blockIdx.x * 16;
  const float* b2 = suf ? b2_b : b2_a;
  const float* W3 = suf ? W3_b : W3_a;
  const float* b3 = suf ? b3_b : b3_a;
  float*     outp = suf ? out_b : out_a;
  const unsigned short* w2h = w2base + (size_t)suf * 131072;
  const unsigned short* w2l = w2base + W2SPLIT_N + (size_t)suf * 131072;

  for (int l = t; l < 2048; l += 256) rtm[l] = ws[WS_RT + suf * 2048 + l];
  float g0 = ws[WS_GS + suf * 2 + 0];
  float g1 = ws[WS_GS + suf * 2 + 1];
  __syncthreads();

  // ---- phase 1: maxout over p, mixture over k -> m1f (16 rows) ----
  {
    int row = t >> 4, c8 = (t & 15) * 8;
    const float* p0 = z0 + ((size_t)(suf * 2 + 0) * MM + m0 + row) * 1024 + c8;
    const float* p1 = z0 + ((size_t)(suf * 2 + 1) * MM + m0 + row) * 1024 + c8;
    float4 mxa0 = {NEG_INF, NEG_INF, NEG_INF, NEG_INF}, mxb0 = mxa0;
    float4 mxa1 = mxa0, mxb1 = mxa0;
#pragma unroll
    for (int pp = 0; pp < 8; ++pp) {
      float4 va0 = *(const float4*)&p0[pp * 128];
      float4 vb0 = *(const float4*)&p0[pp * 128 + 4];
      float4 ra0 = *(const float4*)&rtm[pp * 128 + c8];
      float4 rb0 = *(const float4*)&rtm[pp * 128 + c8 + 4];
      mxa0.x = fmaxf(mxa0.x, va0.x + ra0.x); mxa0.y = fmaxf(mxa0.y, va0.y + ra0.y);
      mxa0.z = fmaxf(mxa0.z, va0.z + ra0.z); mxa0.w = fmaxf(mxa0.w, va0.w + ra0.w);
      mxb0.x = fmaxf(mxb0.x, vb0.x + rb0.x); mxb0.y = fmaxf(mxb0.y, vb0.y + rb0.y);
      mxb0.z = fmaxf(mxb0.z, vb0.z + rb0.z); mxb0.w = fmaxf(mxb0.w, vb0.w + rb0.w);
      float4 va1 = *(const float4*)&p1[pp * 128];
      float4 vb1 = *(const float4*)&p1[pp * 128 + 4];
      float4 ra1 = *(const float4*)&rtm[1024 + pp * 128 + c8];
      float4 rb1 = *(const float4*)&rtm[1024 + pp * 128 + c8 + 4];
      mxa1.x = fmaxf(mxa1.x, va1.x + ra1.x); mxa1.y = fmaxf(mxa1.y, va1.y + ra1.y);
      mxa1.z = fmaxf(mxa1.z, va1.z + ra1.z); mxa1.w = fmaxf(mxa1.w, va1.w + ra1.w);
      mxb1.x = fmaxf(mxb1.x, vb1.x + rb1.x); mxb1.y = fmaxf(mxb1.y, vb1.y + rb1.y);
      mxb1.z = fmaxf(mxb1.z, vb1.z + rb1.z); mxb1.w = fmaxf(mxb1.w, vb1.w + rb1.w);
    }
    float4 o0 = {g0 * mxa0.x + g1 * mxa1.x, g0 * mxa0.y + g1 * mxa1.y,
                 g0 * mxa0.z + g1 * mxa1.z, g0 * mxa0.w + g1 * mxa1.w};
    float4 o1 = {g0 * mxb0.x + g1 * mxb1.x, g0 * mxb0.y + g1 * mxb1.y,
                 g0 * mxb0.z + g1 * mxb1.z, g0 * mxb0.w + g1 * mxb1.w};
    *(float4*)&m1f[row][c8] = o0;
    *(float4*)&m1f[row][c8 + 4] = o1;
  }
  __syncthreads();

  // ---- A fragments: split m1 rows hi/lo in registers ----
  int lane = t & 63, wid = t >> 6;
  int wcol = wid * 32;
  int lr = lane & 15, lk = (lane >> 4) * 8, lq = lane >> 4;
  bf16x8 ah[4], al[4];
#pragma unroll
  for (int kk = 0; kk < 4; ++kk) {
    float4 x0 = *(const float4*)&m1f[lr][kk * 32 + lk];
    float4 x1 = *(const float4*)&m1f[lr][kk * 32 + lk + 4];
    u16x4 h0, l0, h1, l1;
    split4(x0, &h0, &l0); split4(x1, &h1, &l1);
    bf16x8 a, b;
#pragma unroll
    for (int j = 0; j < 4; ++j) { a[j] = (short)h0[j]; a[4 + j] = (short)h1[j]; }
#pragma unroll
    for (int j = 0; j < 4; ++j) { b[j] = (short)l0[j]; b[4 + j] = (short)l1[j]; }
    ah[kk] = a; al[kk] = b;
  }

  // ---- phase 2: split-bf16 MFMA, B from global L2, maxout over sp ----
  float m2x[2][4];
#pragma unroll
  for (int nt = 0; nt < 2; ++nt)
#pragma unroll
    for (int r = 0; r < 4; ++r) m2x[nt][r] = NEG_INF;

  for (int sp = 0; sp < 8; ++sp) {
    f32x4 zz = {0.f, 0.f, 0.f, 0.f};
    f32x4 acc[2][2] = {{zz, zz}, {zz, zz}};
#pragma unroll
    for (int kk = 0; kk < 4; ++kk)
#pragma unroll
      for (int nt = 0; nt < 2; ++nt) {
        size_t boff = (size_t)(sp * 128 + wcol + nt * 16 + lr) * 128 + kk * 32 + lk;
        bf16x8 bhf = *(const bf16x8*)&w2h[boff];
        bf16x8 blf = *(const bf16x8*)&w2l[boff];
        int par = kk & 1;
        acc[nt][par] = __builtin_amdgcn_mfma_f32_16x16x32_bf16(ah[kk], bhf, acc[nt][par], 0, 0, 0);
        acc[nt][par] = __builtin_amdgcn_mfma_f32_16x16x32_bf16(ah[kk], blf, acc[nt][par], 0, 0, 0);
        acc[nt][par] = __builtin_amdgcn_mfma_f32_16x16x32_bf16(al[kk], bhf, acc[nt][par], 0, 0, 0);
      }
#pragma unroll
    for (int nt = 0; nt < 2; ++nt) {
      float bias = b2[sp * 128 + wcol + nt * 16 + lr];
#pragma unroll
      for (int r = 0; r < 4; ++r)
        m2x[nt][r] = fmaxf(m2x[nt][r], acc[nt][0][r] + acc[nt][1][r] + bias);
    }
  }
#pragma unroll
  for (int nt = 0; nt < 2; ++nt)
#pragma unroll
    for (int r = 0; r < 4; ++r)
      m2f[lq * 4 + r][wcol + nt * 16 + lr] = m2x[nt][r];
  __syncthreads();

  // ---- phase 3: [m1|m2] @ W3^T + b3, max over 8 ----
  if (t < 128) {
    int row = t & 15, jp = t >> 4;
    const float* w3 = W3 + jp * 256;
    float acc = b3[jp];
    for (int f = 0; f < 128; f += 4) {
      float4 w = *(const float4*)&w3[f];
      acc += w.x * m1f[row][f] + w.y * m1f[row][f + 1] + w.z * m1f[row][f + 2] + w.w * m1f[row][f + 3];
    }
    for (int f = 0; f < 128; f += 4) {
      float4 w = *(const float4*)&w3[128 + f];
      acc += w.x * m2f[row][f] + w.y * m2f[row][f + 1] + w.z * m2f[row][f + 2] + w.w * m2f[row][f + 3];
    }
    sj[row][jp] = acc;
  }
  __syncthreads();
  if (t < 16) {
    float mx = sj[t][0];
#pragma unroll
    for (int j = 1; j < 8; ++j) mx = fmaxf(mx, sj[t][j]);
    outp[m0 + t] = mx;
  }
}

// =====================================================================
// slow fallback (tiny ws)
// =====================================================================
__global__ void k_score_slow(
    const float* __restrict__ U,
    const float* __restrict__ We_a, const float* __restrict__ We_b,
    const float* __restrict__ W2_a, const float* __restrict__ b2_a,
    const float* __restrict__ W3_a, const float* __restrict__ b3_a,
    const float* __restrict__ W2_b, const float* __restrict__ b2_b,
    const float* __restrict__ W3_b, const float* __restrict__ b3_b,
    float* __restrict__ out_a, float* __restrict__ out_b,
    const float* __restrict__ ws) {
  __shared__ float u[256];
  __shared__ float m1s[128];
  __shared__ float m2v[1024];
  __shared__ float m2s[128];
  __shared__ float sjs[8];
  int t = threadIdx.x;
  int m = blockIdx.x;
  int suf = blockIdx.y;
  const float* We = suf ? We_b : We_a;
  const float* W2 = suf ? W2_b : W2_a;
  const float* b2 = suf ? b2_b : b2_a;
  const float* W3 = suf ? W3_b : W3_a;
  const float* b3 = suf ? b3_b : b3_a;
  float*     outp = suf ? out_b : out_a;
  float g0 = ws[WS_GS + suf * 2 + 0];
  float g1 = ws[WS_GS + suf * 2 + 1];
  const float* rt = ws + WS_RT + suf * 2048;

  u[t] = U[(size_t)m * 256 + t];
  __syncthreads();
  if (t < 128) {
    float mx[2] = {NEG_INF, NEG_INF};
    for (int k = 0; k < 2; ++k)
      for (int pp = 0; pp < 8; ++pp) {
        int e = k * 1024 + pp * 128 + t;
        const float* w = We + (size_t)e * 384;
        float acc = rt[e];
        for (int f = 0; f < 256; f += 4) {
          float4 wv = *(const float4*)&w[f];
          acc += wv.x * u[f] + wv.y * u[f + 1] + wv.z * u[f + 2] + wv.w * u[f + 3];
        }
        mx[k] = fmaxf(mx[k], acc);
      }
    m1s[t] = g0 * mx[0] + g1 * mx[1];
  }
  __syncthreads();
  for (int e = t; e < 1024; e += 256) {
    const float* w = W2 + (size_t)e * 128;
    float acc = b2[e];
    for (int f = 0; f < 128; f += 4) {
      float4 wv = *(const float4*)&w[f];
      acc += wv.x * m1s[f] + wv.y * m1s[f + 1] + wv.z * m1s[f + 2] + wv.w * m1s[f + 3];
    }
    m2v[e] = acc;
  }
  __syncthreads();
  if (t < 128) {
    float mx = NEG_INF;
    for (int pp = 0; pp < 8; ++pp) mx = fmaxf(mx, m2v[pp * 128 + t]);
    m2s[t] = mx;
  }
  __syncthreads();
  if (t < 8) {
    const float* w3 = W3 + t * 256;
    float acc = b3[t];
    for (int f = 0; f < 128; ++f) acc += w3[f] * m1s[f];
    for (int f = 0; f < 128; ++f) acc += w3[128 + f] * m2s[f];
    sjs[t] = acc;
  }
  __syncthreads();
  if (t == 0) {
    float mx = sjs[0];
    for (int j = 1; j < 8; ++j) mx = fmaxf(mx, sjs[j]);
    outp[m] = mx;
  }
}

// =====================================================================
extern "C" void kernel_launch(void* const* d_in, const int* in_sizes, int n_in,
                              void* d_out, int out_size, void* d_ws, size_t ws_size,
                              hipStream_t stream) {
  const float* U    = (const float*)d_in[0];
  const float* Wih  = (const float*)d_in[1];
  const float* Whh  = (const float*)d_in[2];
  const float* bih  = (const float*)d_in[3];
  const float* bhh  = (const float*)d_in[4];
  const float* Wr_s = (const float*)d_in[5];
  const float* br_s = (const float*)d_in[6];
  const float* Wg_s = (const float*)d_in[7];
  const float* bg_s = (const float*)d_in[8];
  const float* We_s = (const float*)d_in[9];
  const float* be_s = (const float*)d_in[10];
  const float* W2_s = (const float*)d_in[11];
  const float* b2_s = (const float*)d_in[12];
  const float* W3_s = (const float*)d_in[13];
  const float* b3_s = (const float*)d_in[14];
  const float* Wr_e = (const float*)d_in[15];
  const float* br_e = (const float*)d_in[16];
  const float* Wg_e = (const float*)d_in[17];
  const float* bg_e = (const float*)d_in[18];
  const float* We_e = (const float*)d_in[19];
  const float* be_e = (const float*)d_in[20];
  const float* W2_e = (const float*)d_in[21];
  const float* b2_e = (const float*)d_in[22];
  const float* W3_e = (const float*)d_in[23];
  const float* b3_e = (const float*)d_in[24];
  float* out = (float*)d_out;
  float* ws  = (float*)d_ws;

  int fast4 = (ws_size >= (size_t)WS_END4 * 4);
  int fast2 = (ws_size >= (size_t)WS_END2 * 4);

  if (fast2) {
    k_prep<<<768, 256, 0, stream>>>(W2_s, W2_e, U, We_s, We_e, fast4, ws);
    if (fast4) {
      k_z0m2<<<dim3(32, 8, 4), 256, 0, stream>>>(ws);
    } else {
      k_z0m<<<dim3(32, 8, 4), 256, 0, stream>>>(U, We_s, We_e, ws);
    }
  } else {
    k_init<<<1, 128, 0, stream>>>(ws);
  }

  for (int step = 0; step < NSTEP; ++step) {
    k_gates<<<32, 256, 0, stream>>>(U, Wih, Whh, bih, bhh, out, step, ws);
    k_r<<<17, 256, 0, stream>>>(U, Wr_s, br_s, Wg_s, bg_s,
                                Wr_e, br_e, Wg_e, bg_e, step, ws);
    k_rt<<<64, 256, 0, stream>>>(We_s, be_s, We_e, be_e, ws);

    float* out_s = out + (size_t)step * MM;
    float* out_e = out + (size_t)NSTEP * MM + (size_t)step * MM;

    if (fast2) {
      k_score3<<<dim3(256, 2), 256, 0, stream>>>(
          b2_s, W3_s, b3_s, b2_e, W3_e, b3_e, out_s, out_e, ws);
    } else {
      k_score_slow<<<dim3(MM, 2), 256, 0, stream>>>(
          U, We_s, We_e,
          W2_s, b2_s, W3_s, b3_s,
          W2_e, b2_e, W3_e, b3_e,
          out_s, out_e, ws);
    }
  }
}